// Round 5
// baseline (800.146 us; speedup 1.0000x reference)
//
#include <hip/hip_runtime.h>

#define T_TOK 8192
#define DIM   1024
#define HDIM  4096
#define NE    8
#define BK    64
// gemm1: 256x256 8-phase tiles; gemm2: 128x128 m97 tiles
#define BM1 256
#define BN1 256
#define NT1 (DIM / BK)                  // 16 K-tiles in gemm1
#define BM2 128
#define BN2 128
#define SLOT_CAP (T_TOK * 2 + NE * BM1) // 18432 = 72*256 = 144*128
#define T1M (SLOT_CAP / BM1)            // 72
#define T2M (SLOT_CAP / BM2)            // 144
#define LDS1_BYTES 131072

typedef float        f32x4 __attribute__((ext_vector_type(4)));
typedef unsigned int u32x4 __attribute__((ext_vector_type(4)));

__device__ inline unsigned short f2bf(float f) {
  union { float f; unsigned int u; } a; a.f = f;
  unsigned int u = a.u;
  unsigned int r = (u + 0x7FFFu + ((u >> 16) & 1u)) >> 16;  // RNE
  return (unsigned short)r;
}

__device__ inline f32x4 mfma_bf16_16x16x32(u32x4 a, u32x4 b, f32x4 c) {
  asm("v_mfma_f32_16x16x32_bf16 %0, %1, %2, %0" : "+v"(c) : "v"(a), "v"(b));
  return c;
}

__device__ inline void gload_lds16(const void* g, void* l) {
  __builtin_amdgcn_global_load_lds(
      (const __attribute__((address_space(1))) void*)g,
      (__attribute__((address_space(3))) void*)l, 16, 0, 0);
}

// gelu(v) = v * sigmoid(2*c*(v + 0.044715 v^3))  (tanh-form identity)
__device__ inline float gelu_fast(float v) {
  const float c2 = 1.5957691216057308f;   // 2*sqrt(2/pi)
  float z = c2 * (v + 0.044715f * v * v * v);
  return v / (1.0f + __expf(-z));
}

// ---- x fp32 -> bf16 -------------------------------------------------------
__global__ __launch_bounds__(256) void convert_x_kernel(const float* __restrict__ x,
                                                        unsigned short* __restrict__ xb) {
  size_t i = ((size_t)blockIdx.x * 256 + threadIdx.x) * 4;
  f32x4 v = *(const f32x4*)(x + i);
  unsigned long long p = (unsigned long long)f2bf(v[0])
                       | ((unsigned long long)f2bf(v[1]) << 16)
                       | ((unsigned long long)f2bf(v[2]) << 32)
                       | ((unsigned long long)f2bf(v[3]) << 48);
  *(unsigned long long*)(xb + i) = p;
}

// ---- per-expert transpose: src fp32 [E][R][C] -> dst bf16 [E][C][R] -------
__global__ __launch_bounds__(256) void transpose_bf16_kernel(const float* __restrict__ src,
                                                             unsigned short* __restrict__ dst,
                                                             int R, int C) {
  __shared__ float tile[64][65];
  int e  = blockIdx.z;
  int c0 = blockIdx.x * 64, r0 = blockIdx.y * 64;
  int c  = threadIdx.x & 63, r4 = threadIdx.x >> 6;
  const float* s = src + (size_t)e * R * C;
#pragma unroll
  for (int i = 0; i < 16; i++) {
    int r = r4 + i * 4;
    tile[r][c] = s[(size_t)(r0 + r) * C + (c0 + c)];
  }
  __syncthreads();
  int cc = (threadIdx.x & 31) * 2;
  int rb = threadIdx.x >> 5;
  unsigned short* d = dst + (size_t)e * R * C;
#pragma unroll
  for (int i = 0; i < 8; i++) {
    int rr = rb + i * 8;
    unsigned int p = (unsigned int)f2bf(tile[cc][rr])
                   | ((unsigned int)f2bf(tile[cc + 1][rr]) << 16);
    *(unsigned int*)(d + (size_t)(c0 + rr) * R + (r0 + cc)) = p;
  }
}

// ---- routing: logits, top-2, weights, counts ------------------------------
__global__ __launch_bounds__(256) void routing_kernel(const float* __restrict__ x,
                                                      const float* __restrict__ Wg,
                                                      int* __restrict__ tok_e,
                                                      float* __restrict__ tok_w,
                                                      int* __restrict__ counts) {
  int tok  = (blockIdx.x * 256 + threadIdx.x) >> 6;
  int lane = threadIdx.x & 63;
  const float* xr = x + (size_t)tok * DIM;
  float acc[NE];
#pragma unroll
  for (int e = 0; e < NE; e++) acc[e] = 0.f;
  for (int d = lane; d < DIM; d += 64) {
    float xv = xr[d];
    const float* wr = Wg + d * NE;
#pragma unroll
    for (int e = 0; e < NE; e++) acc[e] += xv * wr[e];
  }
#pragma unroll
  for (int e = 0; e < NE; e++) {
#pragma unroll
    for (int off = 32; off > 0; off >>= 1) acc[e] += __shfl_xor(acc[e], off);
  }
  if (lane == 0) {
    int i0 = 0;
#pragma unroll
    for (int e = 1; e < NE; e++) if (acc[e] > acc[i0]) i0 = e;
    int i1 = (i0 == 0) ? 1 : 0;
#pragma unroll
    for (int e = 0; e < NE; e++) if (e != i0 && acc[e] > acc[i1]) i1 = e;
    float w0 = 1.0f / (1.0f + expf(acc[i1] - acc[i0]));
    float w1 = 1.0f - w0;
    tok_e[tok * 2]     = i0;
    tok_e[tok * 2 + 1] = i1;
    tok_w[tok * 2]     = w0;
    tok_w[tok * 2 + 1] = w1;
    atomicAdd(&counts[i0], 1);
    atomicAdd(&counts[i1], 1);
  }
}

// ---- padded (256-aligned) segment offsets ---------------------------------
__global__ void offsets_kernel(const int* __restrict__ counts, int* __restrict__ offs) {
  if (threadIdx.x == 0 && blockIdx.x == 0) {
    int acc = 0; offs[0] = 0;
    for (int e = 0; e < NE; e++) {
      acc += (counts[e] + BM1 - 1) / BM1 * BM1;
      offs[e + 1] = acc;
    }
  }
}

// ---- scatter token ids into expert segments; record token->slot map -------
__global__ __launch_bounds__(256) void scatter_kernel(const int* __restrict__ tok_e,
                                                      const int* __restrict__ offs,
                                                      int* __restrict__ cursors,
                                                      int* __restrict__ slot_token,
                                                      int* __restrict__ tok_slot) {
  int t = blockIdx.x * 256 + threadIdx.x;
#pragma unroll
  for (int j = 0; j < 2; j++) {
    int e = tok_e[t * 2 + j];
    int pos = atomicAdd(&cursors[e], 1);
    int s = offs[e] + pos;
    slot_token[s] = t;
    tok_slot[t * 2 + j] = s;
  }
}

// ===========================================================================
// GEMM1: 256x256 8-phase schedule (m201 ledger, re-derived):
//  - 512 thr = 8 waves (wr=w>>2 in {0,1}, wc=w&3 in {0..3}); wave out 128x64.
//  - LDS 128KB: A/B double-buffered [256][64] bf16, linear rows; XOR swizzle
//    carried in the GLOBAL source chunk; ds_read un-swizzles (rule #21).
//  - B fragments register-resident per K-tile (read LDS-B only at phase 0)
//    -> B LDS region free from phase 1 onward.
//  - Stagger: phase0 issues {A,B}(t+1).Q3 ; phase q in 1..3 issues
//    {A,B}(t+2).Q(q-1).  Every region issued strictly after a barrier that
//    follows its last reader phase (race-free by program order).
//  - ONE s_waitcnt vmcnt(6) per K-tile (end of phase 3): the 6 newest loads
//    (t+2.Q0-2) stay in flight; forces t+1 complete.  4-7 phase flight time.
// ===========================================================================
__global__ __launch_bounds__(512, 2) void gemm1_kernel(const unsigned short* __restrict__ Xb,
                                                       const unsigned short* __restrict__ W1T,
                                                       const float* __restrict__ b1,
                                                       const int* __restrict__ slot_token,
                                                       const int* __restrict__ offs,
                                                       unsigned short* __restrict__ Hbuf) {
  extern __shared__ __align__(16) unsigned short smem[];
  unsigned short* ldsA0 = smem;
  unsigned short* ldsA1 = smem + 16384;
  unsigned short* ldsB0 = smem + 32768;
  unsigned short* ldsB1 = smem + 49152;

  int gx = gridDim.x;
  int lin = blockIdx.y * gx + blockIdx.x;
  int cpx = (gx * gridDim.y) >> 3;
  int wk  = (lin & 7) * cpx + (lin >> 3);
  int bx = wk % gx, by = wk / gx;

  int row0 = bx * BM1;
  if (row0 >= offs[NE]) return;
  int e = 0;
#pragma unroll
  for (int i = 1; i < NE; i++) if (row0 >= offs[i]) e = i;
  int n0 = by * BN1;

  int tid = threadIdx.x, lane = tid & 63, w = tid >> 6;
  int wr = w >> 2, wc = w & 3;

  // staging geometry: per quarter, wave-uniform LDS base + per-lane global src
  int ch = (lane & 7) ^ (lane >> 3);     // pre-swizzled global 16B-chunk
  const unsigned short* aQ[4];
  const unsigned short* bQ[4];
  int aDb[4], bDb[4];
#pragma unroll
  for (int q = 0; q < 4; q++) {
    int arow0 = q * 32 + (w & 3) * 8 + (w >> 2) * 128;   // wave-uniform, %8==0
    int arow  = arow0 + (lane >> 3);
    int tk = slot_token[row0 + arow]; if (tk < 0) tk = 0;
    aQ[q]  = Xb + (size_t)tk * DIM + ch * 8;
    aDb[q] = arow0 * 64;
    int brow0 = q * 64 + w * 8;                          // wave-uniform, %8==0
    bQ[q]  = W1T + ((size_t)e * HDIM + n0 + brow0 + (lane >> 3)) * DIM + ch * 8;
    bDb[q] = brow0 * 64;
  }

  int frow = lane & 15, hi = lane >> 4;
  int cs0 = (hi ^ (lane & 7)) * 8;         // kk=0 physical chunk offset (elems)
  int cs1 = ((4 + hi) ^ (lane & 7)) * 8;   // kk=1
  int aro[8], bro[4];
#pragma unroll
  for (int m = 0; m < 8; m++) aro[m] = (wr * 128 + m * 16 + frow) * 64;
#pragma unroll
  for (int n = 0; n < 4; n++) bro[n] = (wc * 64 + n * 16 + frow) * 64;

  f32x4 acc[8][4];
#pragma unroll
  for (int m = 0; m < 8; m++)
#pragma unroll
    for (int n = 0; n < 4; n++) acc[m][n] = 0.f;

  // prologue: tile0 Q0-3 -> buf0, tile1 Q0-2 -> buf1 (14 loads/wave)
#pragma unroll
  for (int q = 0; q < 4; q++) {
    gload_lds16(aQ[q], ldsA0 + aDb[q]); aQ[q] += BK;
    gload_lds16(bQ[q], ldsB0 + bDb[q]); bQ[q] += BK;
  }
#pragma unroll
  for (int q = 0; q < 3; q++) {
    gload_lds16(aQ[q], ldsA1 + aDb[q]); aQ[q] += BK;
    gload_lds16(bQ[q], ldsB1 + bDb[q]); bQ[q] += BK;
  }
  asm volatile("s_waitcnt vmcnt(6)" ::: "memory");
  __builtin_amdgcn_s_barrier();

#pragma unroll 1
  for (int t = 0; t < NT1; ++t) {
    unsigned short* At = (t & 1) ? ldsA1 : ldsA0;
    unsigned short* Bt = (t & 1) ? ldsB1 : ldsB0;
    unsigned short* An = (t & 1) ? ldsA0 : ldsA1;
    unsigned short* Bn = (t & 1) ? ldsB0 : ldsB1;
    u32x4 breg[4][2], areg[2][2];

    // ---------------- phase 0: issue (t+1).Q3; read B-all + A.Q0 ----------
    if (t + 1 < NT1) {
      gload_lds16(aQ[3], An + aDb[3]); aQ[3] += BK;
      gload_lds16(bQ[3], Bn + bDb[3]); bQ[3] += BK;
    }
#pragma unroll
    for (int n = 0; n < 4; n++) {
      breg[n][0] = *(const u32x4*)(Bt + bro[n] + cs0);
      breg[n][1] = *(const u32x4*)(Bt + bro[n] + cs1);
    }
#pragma unroll
    for (int mm = 0; mm < 2; mm++) {
      areg[mm][0] = *(const u32x4*)(At + aro[mm] + cs0);
      areg[mm][1] = *(const u32x4*)(At + aro[mm] + cs1);
    }
    __builtin_amdgcn_s_barrier();
    __builtin_amdgcn_s_setprio(1);
#pragma unroll
    for (int mm = 0; mm < 2; mm++)
#pragma unroll
      for (int n = 0; n < 4; n++) {
        acc[mm][n] = mfma_bf16_16x16x32(areg[mm][0], breg[n][0], acc[mm][n]);
        acc[mm][n] = mfma_bf16_16x16x32(areg[mm][1], breg[n][1], acc[mm][n]);
      }
    __builtin_amdgcn_s_setprio(0);
    __builtin_amdgcn_s_barrier();

    // ---------------- phases 1..3: issue (t+2).Q(q-1); read A.Qq ----------
#pragma unroll
    for (int q = 1; q < 4; q++) {
      if (t + 2 < NT1) {
        gload_lds16(aQ[q - 1], At + aDb[q - 1]); aQ[q - 1] += BK;
        gload_lds16(bQ[q - 1], Bt + bDb[q - 1]); bQ[q - 1] += BK;
      }
#pragma unroll
      for (int mm = 0; mm < 2; mm++) {
        areg[mm][0] = *(const u32x4*)(At + aro[q * 2 + mm] + cs0);
        areg[mm][1] = *(const u32x4*)(At + aro[q * 2 + mm] + cs1);
      }
      __builtin_amdgcn_s_barrier();
      __builtin_amdgcn_s_setprio(1);
#pragma unroll
      for (int mm = 0; mm < 2; mm++)
#pragma unroll
        for (int n = 0; n < 4; n++) {
          acc[q * 2 + mm][n] = mfma_bf16_16x16x32(areg[mm][0], breg[n][0], acc[q * 2 + mm][n]);
          acc[q * 2 + mm][n] = mfma_bf16_16x16x32(areg[mm][1], breg[n][1], acc[q * 2 + mm][n]);
        }
      __builtin_amdgcn_s_setprio(0);
      if (q == 3 && t + 1 < NT1) {
        if (t + 2 < NT1) asm volatile("s_waitcnt vmcnt(6)" ::: "memory");
        else             asm volatile("s_waitcnt vmcnt(0)" ::: "memory");
      }
      __builtin_amdgcn_s_barrier();
    }
  }

  // epilogue: bias + gelu -> bf16 Hbuf
  int rb = hi * 4;
#pragma unroll
  for (int n = 0; n < 4; n++) {
    int col = n0 + wc * 64 + n * 16 + frow;
    float bias = b1[e * HDIM + col];
#pragma unroll
    for (int m = 0; m < 8; m++) {
#pragma unroll
      for (int j = 0; j < 4; j++) {
        int gr = row0 + wr * 128 + m * 16 + rb + j;
        Hbuf[(size_t)gr * HDIM + col] = f2bf(gelu_fast(acc[m][n][j] + bias));
      }
    }
  }
}

// ---- GEMM2 (m97 128x128, unchanged from round 4): Y[slot] = h@W2T[e]+b2 ---
__global__ __launch_bounds__(256) void gemm2_kernel(const unsigned short* __restrict__ Hbuf,
                                                    const unsigned short* __restrict__ W2T,
                                                    const float* __restrict__ b2,
                                                    const int* __restrict__ offs,
                                                    float* __restrict__ Ybuf) {
  __shared__ __align__(16) unsigned short As[BM2][BK];
  __shared__ __align__(16) unsigned short Bs[BN2][BK];
  int gx = gridDim.x;
  int lin = blockIdx.y * gx + blockIdx.x;
  int cpx = (gx * gridDim.y) >> 3;
  int wk  = (lin & 7) * cpx + (lin >> 3);
  int bx = wk % gx, by = wk / gx;

  int row0 = bx * BM2;
  if (row0 >= offs[NE]) return;
  int e = 0;
#pragma unroll
  for (int i = 1; i < NE; i++) if (row0 >= offs[i]) e = i;
  int n0  = by * BN2;
  int tid  = threadIdx.x;
  int lane = tid & 63;
  int w    = tid >> 6;
  int wr = tid >> 7;
  int wc = (tid >> 6) & 1;

  int lr  = lane >> 3;
  int lcx = (lane & 7) ^ lr;
  const unsigned short* aG[4];
  const unsigned short* bG[4];
  unsigned short* aL[4];
  unsigned short* bL[4];
#pragma unroll
  for (int i = 0; i < 4; i++) {
    int r = w * 32 + i * 8;
    aG[i] = Hbuf + (size_t)(row0 + r + lr) * HDIM + lcx * 8;
    bG[i] = W2T + ((size_t)e * DIM + n0 + r + lr) * HDIM + lcx * 8;
    aL[i] = &As[r][0];
    bL[i] = &Bs[r][0];
  }

  int frow = lane & 15;
  int kxs  = ((lane >> 4) * 8) ^ ((lane & 7) << 3);

  f32x4 acc[4][4];
#pragma unroll
  for (int m = 0; m < 4; m++)
#pragma unroll
    for (int n = 0; n < 4; n++) acc[m][n] = 0.f;

  for (int k0 = 0; k0 < HDIM; k0 += BK) {
#pragma unroll
    for (int i = 0; i < 4; i++) gload_lds16(aG[i] + k0, aL[i]);
#pragma unroll
    for (int i = 0; i < 4; i++) gload_lds16(bG[i] + k0, bL[i]);
    __syncthreads();
#pragma unroll
    for (int kk = 0; kk < 2; kk++) {
      int col = (kk * 32) ^ kxs;
      u32x4 a[4], b[4];
#pragma unroll
      for (int m = 0; m < 4; m++)
        a[m] = *(const u32x4*)&As[wr * 64 + m * 16 + frow][col];
#pragma unroll
      for (int n = 0; n < 4; n++)
        b[n] = *(const u32x4*)&Bs[wc * 64 + n * 16 + frow][col];
#pragma unroll
      for (int m = 0; m < 4; m++)
#pragma unroll
        for (int n = 0; n < 4; n++)
          acc[m][n] = mfma_bf16_16x16x32(a[m], b[n], acc[m][n]);
    }
    __syncthreads();
  }

  int rbase = (lane >> 4) * 4;
  int cbase = lane & 15;
#pragma unroll
  for (int m = 0; m < 4; m++) {
#pragma unroll
    for (int n = 0; n < 4; n++) {
      int dcol = n0 + wc * 64 + n * 16 + cbase;
      float bias = b2[e * DIM + dcol];
#pragma unroll
      for (int j = 0; j < 4; j++) {
        int gr = row0 + wr * 64 + m * 16 + rbase + j;
        Ybuf[(size_t)gr * DIM + dcol] = acc[m][n][j] + bias;
      }
    }
  }
}

// ---- combine: out[t] = w0*Y[s0] + w1*Y[s1] --------------------------------
__global__ __launch_bounds__(256) void combine_kernel(const float* __restrict__ Ybuf,
                                                      const int* __restrict__ tok_slot,
                                                      const float* __restrict__ tok_w,
                                                      float* __restrict__ out) {
  int t = blockIdx.x;
  int c = threadIdx.x * 4;
  int s0 = tok_slot[t * 2], s1 = tok_slot[t * 2 + 1];
  float w0 = tok_w[t * 2], w1 = tok_w[t * 2 + 1];
  f32x4 y0 = *(const f32x4*)(Ybuf + (size_t)s0 * DIM + c);
  f32x4 y1 = *(const f32x4*)(Ybuf + (size_t)s1 * DIM + c);
  f32x4 r;
#pragma unroll
  for (int i = 0; i < 4; i++) r[i] = w0 * y0[i] + w1 * y1[i];
  *(f32x4*)(out + (size_t)t * DIM + c) = r;
}

extern "C" void kernel_launch(void* const* d_in, const int* in_sizes, int n_in,
                              void* d_out, int out_size, void* d_ws, size_t ws_size,
                              hipStream_t stream) {
  (void)in_sizes; (void)n_in; (void)out_size;
  const float* x  = (const float*)d_in[0];
  const float* Wg = (const float*)d_in[1];
  const float* W1 = (const float*)d_in[2];
  const float* b1 = (const float*)d_in[3];
  const float* W2 = (const float*)d_in[4];
  const float* b2 = (const float*)d_in[5];
  float* out = (float*)d_out;

  char* ws = (char*)d_ws;
  size_t off = 0;
  auto take = [&](size_t bytes) -> char* {
    char* p = ws + off;
    off += (bytes + 255) & ~(size_t)255;
    return p;
  };
  unsigned short* W1T  = (unsigned short*)take((size_t)NE * DIM * HDIM * 2);
  unsigned short* W2T  = (unsigned short*)take((size_t)NE * DIM * HDIM * 2);
  unsigned short* Xb   = (unsigned short*)take((size_t)T_TOK * DIM * 2);
  unsigned short* Hbuf = (unsigned short*)take((size_t)SLOT_CAP * HDIM * 2);
  float* Ybuf       = (float*)take((size_t)SLOT_CAP * DIM * 4);
  int*   slot_token = (int*)take(SLOT_CAP * 4);
  int*   tok_e      = (int*)take(T_TOK * 2 * 4);
  float* tok_w      = (float*)take(T_TOK * 2 * 4);
  int*   tok_slot   = (int*)take(T_TOK * 2 * 4);
  int*   counts     = (int*)take(256);
  int*   cursors    = (int*)take(256);
  int*   offs       = (int*)take(256);

  if (off > ws_size) {
    hipMemsetAsync(d_out, 0, (size_t)out_size * 4, stream);
    return;
  }

  hipFuncSetAttribute((const void*)gemm1_kernel,
                      hipFuncAttributeMaxDynamicSharedMemorySize, LDS1_BYTES);

  hipMemsetAsync(counts, 0, 256, stream);
  hipMemsetAsync(cursors, 0, 256, stream);
  hipMemsetAsync(slot_token, 0xFF, SLOT_CAP * 4, stream);

  convert_x_kernel<<<T_TOK * DIM / 1024, 256, 0, stream>>>(x, Xb);
  transpose_bf16_kernel<<<dim3(HDIM / 64, DIM / 64, NE), 256, 0, stream>>>(W1, W1T, DIM, HDIM);
  transpose_bf16_kernel<<<dim3(DIM / 64, HDIM / 64, NE), 256, 0, stream>>>(W2, W2T, HDIM, DIM);
  routing_kernel<<<T_TOK / 4, 256, 0, stream>>>(x, Wg, tok_e, tok_w, counts);
  offsets_kernel<<<1, 64, 0, stream>>>(counts, offs);
  scatter_kernel<<<T_TOK / 256, 256, 0, stream>>>(tok_e, offs, cursors, slot_token, tok_slot);
  gemm1_kernel<<<dim3(T1M, HDIM / BN1), 512, LDS1_BYTES, stream>>>(Xb, W1T, b1, slot_token, offs, Hbuf);
  gemm2_kernel<<<dim3(T2M, DIM / BN2), 256, 0, stream>>>(Hbuf, W2T, b2, offs, Ybuf);
  combine_kernel<<<T_TOK, 256, 0, stream>>>(Ybuf, tok_slot, tok_w, out);
}

// Round 6
// 534.773 us; speedup vs baseline: 1.4962x; 1.4962x over previous
//
#include <hip/hip_runtime.h>

#define T_TOK 8192
#define DIM   1024
#define HDIM  4096
#define NE    8
#define BK    64
#define BM    128
#define BN    128
#define SLOT_CAP (T_TOK * 2 + NE * BM)   // 17408 = 136*128
#define TILES (SLOT_CAP / BM)            // 136

typedef float        f32x4 __attribute__((ext_vector_type(4)));
typedef unsigned int u32x4 __attribute__((ext_vector_type(4)));

__device__ inline unsigned short f2bf(float f) {
  union { float f; unsigned int u; } a; a.f = f;
  unsigned int u = a.u;
  unsigned int r = (u + 0x7FFFu + ((u >> 16) & 1u)) >> 16;  // RNE
  return (unsigned short)r;
}

__device__ inline f32x4 mfma_bf16_16x16x32(u32x4 a, u32x4 b, f32x4 c) {
  asm("v_mfma_f32_16x16x32_bf16 %0, %1, %2, %0" : "+v"(c) : "v"(a), "v"(b));
  return c;
}

__device__ inline void gload_lds16(const void* g, void* l) {
  __builtin_amdgcn_global_load_lds(
      (const __attribute__((address_space(1))) void*)g,
      (__attribute__((address_space(3))) void*)l, 16, 0, 0);
}

// gelu(v) = v * sigmoid(2*c*(v + 0.044715 v^3))  (tanh-form identity)
__device__ inline float gelu_fast(float v) {
  const float c2 = 1.5957691216057308f;   // 2*sqrt(2/pi)
  float z = c2 * (v + 0.044715f * v * v * v);
  return v / (1.0f + __expf(-z));
}

// ---- per-expert transpose: src fp32 [E][R][C] -> dst bf16 [E][C][R] -------
__global__ __launch_bounds__(256) void transpose_bf16_kernel(const float* __restrict__ src,
                                                             unsigned short* __restrict__ dst,
                                                             int R, int C) {
  __shared__ float tile[64][65];
  int e  = blockIdx.z;
  int c0 = blockIdx.x * 64, r0 = blockIdx.y * 64;
  int c  = threadIdx.x & 63, r4 = threadIdx.x >> 6;
  const float* s = src + (size_t)e * R * C;
#pragma unroll
  for (int i = 0; i < 16; i++) {
    int r = r4 + i * 4;
    tile[r][c] = s[(size_t)(r0 + r) * C + (c0 + c)];
  }
  __syncthreads();
  int cc = (threadIdx.x & 31) * 2;
  int rb = threadIdx.x >> 5;
  unsigned short* d = dst + (size_t)e * R * C;
#pragma unroll
  for (int i = 0; i < 8; i++) {
    int rr = rb + i * 8;
    unsigned int p = (unsigned int)f2bf(tile[cc][rr])
                   | ((unsigned int)f2bf(tile[cc + 1][rr]) << 16);
    *(unsigned int*)(d + (size_t)(c0 + rr) * R + (r0 + cc)) = p;
  }
}

// ---- routing (fused x->bf16 convert): logits, top-2, weights --------------
__global__ __launch_bounds__(256) void routing_kernel(const float* __restrict__ x,
                                                      const float* __restrict__ Wg,
                                                      int* __restrict__ tok_e,
                                                      float* __restrict__ tok_w,
                                                      unsigned short* __restrict__ xb) {
  int tok  = (blockIdx.x * 256 + threadIdx.x) >> 6;
  int lane = threadIdx.x & 63;
  const float* xr = x + (size_t)tok * DIM;
  float acc[NE];
#pragma unroll
  for (int e = 0; e < NE; e++) acc[e] = 0.f;
  for (int d = lane; d < DIM; d += 64) {
    float xv = xr[d];
    const float* wr = Wg + d * NE;
#pragma unroll
    for (int e = 0; e < NE; e++) acc[e] += xv * wr[e];
  }
#pragma unroll
  for (int e = 0; e < NE; e++) {
#pragma unroll
    for (int off = 32; off > 0; off >>= 1) acc[e] += __shfl_xor(acc[e], off);
  }
  if (lane == 0) {
    int i0 = 0;
#pragma unroll
    for (int e = 1; e < NE; e++) if (acc[e] > acc[i0]) i0 = e;
    int i1 = (i0 == 0) ? 1 : 0;
#pragma unroll
    for (int e = 0; e < NE; e++) if (e != i0 && acc[e] > acc[i1]) i1 = e;
    float w0 = 1.0f / (1.0f + expf(acc[i1] - acc[i0]));
    tok_e[tok * 2]     = i0;
    tok_e[tok * 2 + 1] = i1;
    tok_w[tok * 2]     = w0;
    tok_w[tok * 2 + 1] = 1.0f - w0;
  }
  // fused bf16 conversion: lane covers x[tok][lane*16 .. lane*16+16)
  unsigned short* xo = xb + (size_t)tok * DIM;
#pragma unroll
  for (int i = 0; i < 4; i++) {
    f32x4 v = *(const f32x4*)(xr + lane * 16 + i * 4);
    unsigned long long p = (unsigned long long)f2bf(v[0])
                         | ((unsigned long long)f2bf(v[1]) << 16)
                         | ((unsigned long long)f2bf(v[2]) << 32)
                         | ((unsigned long long)f2bf(v[3]) << 48);
    *(unsigned long long*)(xo + lane * 16 + i * 4) = p;
  }
}

// ---- histogram counts (block-local, 256 global atomics total) -------------
__global__ __launch_bounds__(256) void count_kernel(const int* __restrict__ tok_e,
                                                    int* __restrict__ counts) {
  __shared__ int h[NE];
  if (threadIdx.x < NE) h[threadIdx.x] = 0;
  __syncthreads();
  for (int i = blockIdx.x * 256 + threadIdx.x; i < T_TOK * 2; i += 32 * 256)
    atomicAdd(&h[tok_e[i]], 1);
  __syncthreads();
  if (threadIdx.x < NE) atomicAdd(&counts[threadIdx.x], h[threadIdx.x]);
}

// ---- padded (128-aligned) segment offsets ---------------------------------
__global__ void offsets_kernel(const int* __restrict__ counts, int* __restrict__ offs) {
  if (threadIdx.x == 0 && blockIdx.x == 0) {
    int acc = 0; offs[0] = 0;
    for (int e = 0; e < NE; e++) {
      acc += (counts[e] + BM - 1) / BM * BM;
      offs[e + 1] = acc;
    }
  }
}

// ---- scatter with wave-ballot aggregation (~8 atomics/wave) ---------------
__global__ __launch_bounds__(256) void scatter_kernel(const int* __restrict__ tok_e,
                                                      const int* __restrict__ offs,
                                                      int* __restrict__ cursors,
                                                      int* __restrict__ slot_token,
                                                      int* __restrict__ tok_slot) {
  int t = blockIdx.x * 256 + threadIdx.x;
  int lane = threadIdx.x & 63;
#pragma unroll
  for (int j = 0; j < 2; j++) {
    int e = tok_e[t * 2 + j];
#pragma unroll
    for (int ee = 0; ee < NE; ee++) {
      unsigned long long m = __ballot(e == ee);
      if (e == ee) {
        int leader = __ffsll(m) - 1;
        int base = 0;
        if (lane == leader) base = atomicAdd(&cursors[ee], (int)__popcll(m));
        base = __shfl(base, leader);
        int pos = base + (int)__popcll(m & ((1ULL << lane) - 1ULL));
        int s = offs[ee] + pos;
        slot_token[s] = t;
        tok_slot[t * 2 + j] = s;
      }
    }
  }
}

// ===========================================================================
// GEMM core (m97): 128x128 tile, BK=64, 4 waves, global_load_lds width 16
// into LINEAR [128][64] bf16 LDS; XOR swizzle baked into the GLOBAL source
// chunk; ds_read un-swizzles (rule #21).  Round-2 verified: 0 bank conflicts.
// Block swizzle: lin = HW dispatch order (y*gx+x); wk = (lin&7)*cpx + lin>>3
// (XCD chunks); decompose wk A-PANEL-MAJOR (bx = wk/GY) so the 8..32 blocks
// sharing an A panel run consecutively on one XCD -> A fetched once from HBM.
// ===========================================================================

// ---- GEMM1: h = gelu(x_gathered @ W1T[e] + b1[e]); h bf16 [SLOT_CAP][H] ---
__global__ __launch_bounds__(256) void gemm1_kernel(const unsigned short* __restrict__ Xb,
                                                    const unsigned short* __restrict__ W1T,
                                                    const float* __restrict__ b1,
                                                    const int* __restrict__ slot_token,
                                                    const int* __restrict__ offs,
                                                    unsigned short* __restrict__ Hbuf) {
  __shared__ __align__(16) unsigned short As[BM][BK];
  __shared__ __align__(16) unsigned short Bs[BN][BK];
  const int GY = HDIM / BN;   // 32
  int lin = blockIdx.y * gridDim.x + blockIdx.x;
  int cpx = (TILES * GY) >> 3;
  int wk  = (lin & 7) * cpx + (lin >> 3);
  int bx = wk / GY, by = wk % GY;

  int row0 = bx * BM;
  if (row0 >= offs[NE]) return;
  int e = 0;
#pragma unroll
  for (int i = 1; i < NE; i++) if (row0 >= offs[i]) e = i;
  int n0  = by * BN;
  int tid  = threadIdx.x;
  int lane = tid & 63;
  int w    = tid >> 6;
  int wr = tid >> 7;
  int wc = (tid >> 6) & 1;

  int lr  = lane >> 3;
  int lcx = (lane & 7) ^ lr;
  const unsigned short* aG[4];
  const unsigned short* bG[4];
  unsigned short* aL[4];
  unsigned short* bL[4];
#pragma unroll
  for (int i = 0; i < 4; i++) {
    int r = w * 32 + i * 8;
    int tk = slot_token[row0 + r + lr];
    if (tk < 0) tk = 0;
    aG[i] = Xb + (size_t)tk * DIM + lcx * 8;
    bG[i] = W1T + ((size_t)e * HDIM + n0 + r + lr) * DIM + lcx * 8;
    aL[i] = &As[r][0];
    bL[i] = &Bs[r][0];
  }

  int frow = lane & 15;
  int hi   = lane >> 4;
  int kxs  = (hi * 8) ^ ((lane & 7) << 3);

  f32x4 acc[4][4];
#pragma unroll
  for (int m = 0; m < 4; m++)
#pragma unroll
    for (int n = 0; n < 4; n++) acc[m][n] = 0.f;

  for (int k0 = 0; k0 < DIM; k0 += BK) {
#pragma unroll
    for (int i = 0; i < 4; i++) gload_lds16(aG[i] + k0, aL[i]);
#pragma unroll
    for (int i = 0; i < 4; i++) gload_lds16(bG[i] + k0, bL[i]);
    __syncthreads();
#pragma unroll
    for (int kk = 0; kk < 2; kk++) {
      int col = (kk * 32) ^ kxs;
      u32x4 a[4], b[4];
#pragma unroll
      for (int m = 0; m < 4; m++)
        a[m] = *(const u32x4*)&As[wr * 64 + m * 16 + frow][col];
#pragma unroll
      for (int n = 0; n < 4; n++)
        b[n] = *(const u32x4*)&Bs[wc * 64 + n * 16 + frow][col];
#pragma unroll
      for (int m = 0; m < 4; m++)
#pragma unroll
        for (int n = 0; n < 4; n++)
          acc[m][n] = mfma_bf16_16x16x32(a[m], b[n], acc[m][n]);
    }
    __syncthreads();
  }

  // LDS-staged epilogue: gelu -> bf16 -> [32][136] LDS chunk -> 256B-coalesced
  // row stores (cuts the 2x sector amplification of scalar bf16 stores).
  float bias[4];
#pragma unroll
  for (int n = 0; n < 4; n++) bias[n] = b1[e * HDIM + n0 + wc * 64 + n * 16 + frow];
  unsigned short (*E)[136] = (unsigned short (*)[136])(&As[0][0]);
#pragma unroll
  for (int c0 = 0; c0 < 128; c0 += 32) {
    if (wr == (c0 >> 6)) {
      int mbase = (c0 & 63) >> 4;
#pragma unroll
      for (int mm = 0; mm < 2; mm++) {
        int m = mbase + mm;
#pragma unroll
        for (int n = 0; n < 4; n++)
#pragma unroll
          for (int j = 0; j < 4; j++)
            E[mm * 16 + hi * 4 + j][wc * 64 + n * 16 + frow] =
                f2bf(gelu_fast(acc[m][n][j] + bias[n]));
      }
    }
    __syncthreads();
#pragma unroll
    for (int p = 0; p < 2; p++) {
      int r  = p * 16 + (tid >> 4);
      int cc = (tid & 15) * 8;
      u32x4 v = *(const u32x4*)&E[r][cc];
      *(u32x4*)(Hbuf + (size_t)(row0 + c0 + r) * HDIM + n0 + cc) = v;
    }
    __syncthreads();
  }
}

// ---- GEMM2: Y[slot] = h @ W2T[e] + b2[e] ----------------------------------
__global__ __launch_bounds__(256) void gemm2_kernel(const unsigned short* __restrict__ Hbuf,
                                                    const unsigned short* __restrict__ W2T,
                                                    const float* __restrict__ b2,
                                                    const int* __restrict__ offs,
                                                    float* __restrict__ Ybuf) {
  __shared__ __align__(16) unsigned short As[BM][BK];
  __shared__ __align__(16) unsigned short Bs[BN][BK];
  const int GY = DIM / BN;    // 8
  int lin = blockIdx.y * gridDim.x + blockIdx.x;
  int cpx = (TILES * GY) >> 3;
  int wk  = (lin & 7) * cpx + (lin >> 3);
  int bx = wk / GY, by = wk % GY;

  int row0 = bx * BM;
  if (row0 >= offs[NE]) return;
  int e = 0;
#pragma unroll
  for (int i = 1; i < NE; i++) if (row0 >= offs[i]) e = i;
  int n0  = by * BN;
  int tid  = threadIdx.x;
  int lane = tid & 63;
  int w    = tid >> 6;
  int wr = tid >> 7;
  int wc = (tid >> 6) & 1;

  int lr  = lane >> 3;
  int lcx = (lane & 7) ^ lr;
  const unsigned short* aG[4];
  const unsigned short* bG[4];
  unsigned short* aL[4];
  unsigned short* bL[4];
#pragma unroll
  for (int i = 0; i < 4; i++) {
    int r = w * 32 + i * 8;
    aG[i] = Hbuf + (size_t)(row0 + r + lr) * HDIM + lcx * 8;
    bG[i] = W2T + ((size_t)e * DIM + n0 + r + lr) * HDIM + lcx * 8;
    aL[i] = &As[r][0];
    bL[i] = &Bs[r][0];
  }

  int frow = lane & 15;
  int kxs  = ((lane >> 4) * 8) ^ ((lane & 7) << 3);

  f32x4 acc[4][4];
#pragma unroll
  for (int m = 0; m < 4; m++)
#pragma unroll
    for (int n = 0; n < 4; n++) acc[m][n] = 0.f;

  for (int k0 = 0; k0 < HDIM; k0 += BK) {
#pragma unroll
    for (int i = 0; i < 4; i++) gload_lds16(aG[i] + k0, aL[i]);
#pragma unroll
    for (int i = 0; i < 4; i++) gload_lds16(bG[i] + k0, bL[i]);
    __syncthreads();
#pragma unroll
    for (int kk = 0; kk < 2; kk++) {
      int col = (kk * 32) ^ kxs;
      u32x4 a[4], b[4];
#pragma unroll
      for (int m = 0; m < 4; m++)
        a[m] = *(const u32x4*)&As[wr * 64 + m * 16 + frow][col];
#pragma unroll
      for (int n = 0; n < 4; n++)
        b[n] = *(const u32x4*)&Bs[wc * 64 + n * 16 + frow][col];
#pragma unroll
      for (int m = 0; m < 4; m++)
#pragma unroll
        for (int n = 0; n < 4; n++)
          acc[m][n] = mfma_bf16_16x16x32(a[m], b[n], acc[m][n]);
    }
    __syncthreads();
  }

  int rbase = (lane >> 4) * 4;
  int cbase = lane & 15;
#pragma unroll
  for (int m = 0; m < 4; m++) {
#pragma unroll
    for (int n = 0; n < 4; n++) {
      int dcol = n0 + wc * 64 + n * 16 + cbase;
      float bias = b2[e * DIM + dcol];
#pragma unroll
      for (int j = 0; j < 4; j++) {
        int gr = row0 + wr * 64 + m * 16 + rbase + j;
        Ybuf[(size_t)gr * DIM + dcol] = acc[m][n][j] + bias;
      }
    }
  }
}

// ---- combine: out[t] = w0*Y[s0] + w1*Y[s1] --------------------------------
__global__ __launch_bounds__(256) void combine_kernel(const float* __restrict__ Ybuf,
                                                      const int* __restrict__ tok_slot,
                                                      const float* __restrict__ tok_w,
                                                      float* __restrict__ out) {
  int t = blockIdx.x;
  int c = threadIdx.x * 4;
  int s0 = tok_slot[t * 2], s1 = tok_slot[t * 2 + 1];
  float w0 = tok_w[t * 2], w1 = tok_w[t * 2 + 1];
  f32x4 y0 = *(const f32x4*)(Ybuf + (size_t)s0 * DIM + c);
  f32x4 y1 = *(const f32x4*)(Ybuf + (size_t)s1 * DIM + c);
  f32x4 r;
#pragma unroll
  for (int i = 0; i < 4; i++) r[i] = w0 * y0[i] + w1 * y1[i];
  *(f32x4*)(out + (size_t)t * DIM + c) = r;
}

extern "C" void kernel_launch(void* const* d_in, const int* in_sizes, int n_in,
                              void* d_out, int out_size, void* d_ws, size_t ws_size,
                              hipStream_t stream) {
  (void)in_sizes; (void)n_in; (void)out_size;
  const float* x  = (const float*)d_in[0];
  const float* Wg = (const float*)d_in[1];
  const float* W1 = (const float*)d_in[2];
  const float* b1 = (const float*)d_in[3];
  const float* W2 = (const float*)d_in[4];
  const float* b2 = (const float*)d_in[5];
  float* out = (float*)d_out;

  char* ws = (char*)d_ws;
  size_t off = 0;
  auto take = [&](size_t bytes) -> char* {
    char* p = ws + off;
    off += (bytes + 255) & ~(size_t)255;
    return p;
  };
  unsigned short* W1T  = (unsigned short*)take((size_t)NE * DIM * HDIM * 2);
  unsigned short* W2T  = (unsigned short*)take((size_t)NE * DIM * HDIM * 2);
  unsigned short* Xb   = (unsigned short*)take((size_t)T_TOK * DIM * 2);
  unsigned short* Hbuf = (unsigned short*)take((size_t)SLOT_CAP * HDIM * 2);
  float* Ybuf       = (float*)take((size_t)SLOT_CAP * DIM * 4);
  int*   slot_token = (int*)take(SLOT_CAP * 4);
  int*   tok_e      = (int*)take(T_TOK * 2 * 4);
  float* tok_w      = (float*)take(T_TOK * 2 * 4);
  int*   tok_slot   = (int*)take(T_TOK * 2 * 4);
  int*   counts     = (int*)take(256);
  int*   cursors    = (int*)take(256);
  int*   offs       = (int*)take(256);

  if (off > ws_size) {
    hipMemsetAsync(d_out, 0, (size_t)out_size * 4, stream);
    return;
  }

  hipMemsetAsync(counts, 0, 256, stream);
  hipMemsetAsync(cursors, 0, 256, stream);
  hipMemsetAsync(slot_token, 0xFF, SLOT_CAP * 4, stream);

  routing_kernel<<<T_TOK / 4, 256, 0, stream>>>(x, Wg, tok_e, tok_w, Xb);
  count_kernel<<<32, 256, 0, stream>>>(tok_e, counts);
  offsets_kernel<<<1, 64, 0, stream>>>(counts, offs);
  scatter_kernel<<<T_TOK / 256, 256, 0, stream>>>(tok_e, offs, cursors, slot_token, tok_slot);
  transpose_bf16_kernel<<<dim3(HDIM / 64, DIM / 64, NE), 256, 0, stream>>>(W1, W1T, DIM, HDIM);
  transpose_bf16_kernel<<<dim3(DIM / 64, HDIM / 64, NE), 256, 0, stream>>>(W2, W2T, HDIM, DIM);
  gemm1_kernel<<<dim3(TILES, HDIM / BN), 256, 0, stream>>>(Xb, W1T, b1, slot_token, offs, Hbuf);
  gemm2_kernel<<<dim3(TILES, DIM / BN), 256, 0, stream>>>(Hbuf, W2T, b2, offs, Ybuf);
  combine_kernel<<<T_TOK, 256, 0, stream>>>(Ybuf, tok_slot, tok_w, out);
}

// Round 7
// 531.322 us; speedup vs baseline: 1.5060x; 1.0065x over previous
//
#include <hip/hip_runtime.h>

#define T_TOK 8192
#define DIM   1024
#define HDIM  4096
#define NE    8
#define BK    64
#define BM    128
#define BN    128
#define SLOT_CAP (T_TOK * 2 + NE * BM)   // 17408 = 136*128
#define TILES (SLOT_CAP / BM)            // 136

typedef float        f32x4 __attribute__((ext_vector_type(4)));
typedef unsigned int u32x4 __attribute__((ext_vector_type(4)));

__device__ inline unsigned short f2bf(float f) {
  union { float f; unsigned int u; } a; a.f = f;
  unsigned int u = a.u;
  unsigned int r = (u + 0x7FFFu + ((u >> 16) & 1u)) >> 16;  // RNE
  return (unsigned short)r;
}

__device__ inline f32x4 mfma_bf16_16x16x32(u32x4 a, u32x4 b, f32x4 c) {
  asm("v_mfma_f32_16x16x32_bf16 %0, %1, %2, %0" : "+v"(c) : "v"(a), "v"(b));
  return c;
}

__device__ inline void gload_lds16(const void* g, void* l) {
  __builtin_amdgcn_global_load_lds(
      (const __attribute__((address_space(1))) void*)g,
      (__attribute__((address_space(3))) void*)l, 16, 0, 0);
}

// gelu(v) = v * sigmoid(2*c*(v + 0.044715 v^3))  (tanh-form identity)
__device__ inline float gelu_fast(float v) {
  const float c2 = 1.5957691216057308f;   // 2*sqrt(2/pi)
  float z = c2 * (v + 0.044715f * v * v * v);
  return v / (1.0f + __expf(-z));
}

// padded (128-aligned) expert segment prefix, recomputed locally (8 uniform
// scalar loads — replaces the offsets kernel)
__device__ inline void load_offs(const int* __restrict__ counts, int* offs) {
  offs[0] = 0;
#pragma unroll
  for (int e = 0; e < NE; e++)
    offs[e + 1] = offs[e] + ((counts[e] + BM - 1) / BM) * BM;
}

// ---- per-expert transpose: src fp32 [E][R][C] -> dst bf16 [E][C][R] -------
// write side: 8 bf16 packed per lane -> 16B stores, 128B per 8-lane group
__global__ __launch_bounds__(256) void transpose_bf16_kernel(const float* __restrict__ src,
                                                             unsigned short* __restrict__ dst,
                                                             int R, int C) {
  __shared__ float tile[64][65];
  int e  = blockIdx.z;
  int c0 = blockIdx.x * 64, r0 = blockIdx.y * 64;
  int c  = threadIdx.x & 63, r4 = threadIdx.x >> 6;
  const float* s = src + (size_t)e * R * C;
#pragma unroll
  for (int i = 0; i < 16; i++) {
    int r = r4 + i * 4;
    tile[r][c] = s[(size_t)(r0 + r) * C + (c0 + c)];
  }
  __syncthreads();
  unsigned short* d = dst + (size_t)e * R * C;
  int rbase = (threadIdx.x & 7) * 8;
#pragma unroll
  for (int g = 0; g < 2; g++) {
    int cc = (threadIdx.x >> 3) + g * 32;
    u32x4 v;
#pragma unroll
    for (int k = 0; k < 4; k++)
      v[k] = (unsigned int)f2bf(tile[rbase + 2 * k][cc])
           | ((unsigned int)f2bf(tile[rbase + 2 * k + 1][cc]) << 16);
    *(u32x4*)(d + (size_t)(c0 + cc) * R + (r0 + rbase)) = v;
  }
}

// ---- routing (fused x->bf16 convert + histogram): logits, top-2, weights --
__global__ __launch_bounds__(256) void routing_kernel(const float* __restrict__ x,
                                                      const float* __restrict__ Wg,
                                                      int* __restrict__ tok_e,
                                                      float* __restrict__ tok_w,
                                                      unsigned short* __restrict__ xb,
                                                      int* __restrict__ counts) {
  __shared__ int h[NE];
  if (threadIdx.x < NE) h[threadIdx.x] = 0;
  __syncthreads();
  int tok  = (blockIdx.x * 256 + threadIdx.x) >> 6;
  int lane = threadIdx.x & 63;
  const float* xr = x + (size_t)tok * DIM;
  float acc[NE];
#pragma unroll
  for (int e = 0; e < NE; e++) acc[e] = 0.f;
  for (int d = lane; d < DIM; d += 64) {
    float xv = xr[d];
    const float* wr = Wg + d * NE;
#pragma unroll
    for (int e = 0; e < NE; e++) acc[e] += xv * wr[e];
  }
#pragma unroll
  for (int e = 0; e < NE; e++) {
#pragma unroll
    for (int off = 32; off > 0; off >>= 1) acc[e] += __shfl_xor(acc[e], off);
  }
  if (lane == 0) {
    int i0 = 0;
#pragma unroll
    for (int e = 1; e < NE; e++) if (acc[e] > acc[i0]) i0 = e;
    int i1 = (i0 == 0) ? 1 : 0;
#pragma unroll
    for (int e = 0; e < NE; e++) if (e != i0 && acc[e] > acc[i1]) i1 = e;
    float w0 = 1.0f / (1.0f + expf(acc[i1] - acc[i0]));
    tok_e[tok * 2]     = i0;
    tok_e[tok * 2 + 1] = i1;
    tok_w[tok * 2]     = w0;
    tok_w[tok * 2 + 1] = 1.0f - w0;
    atomicAdd(&h[i0], 1);
    atomicAdd(&h[i1], 1);
  }
  // fused bf16 conversion: lane covers x[tok][lane*16 .. lane*16+16)
  unsigned short* xo = xb + (size_t)tok * DIM;
#pragma unroll
  for (int i = 0; i < 4; i++) {
    f32x4 v = *(const f32x4*)(xr + lane * 16 + i * 4);
    unsigned long long p = (unsigned long long)f2bf(v[0])
                         | ((unsigned long long)f2bf(v[1]) << 16)
                         | ((unsigned long long)f2bf(v[2]) << 32)
                         | ((unsigned long long)f2bf(v[3]) << 48);
    *(unsigned long long*)(xo + lane * 16 + i * 4) = p;
  }
  __syncthreads();
  if (threadIdx.x < NE) atomicAdd(&counts[threadIdx.x], h[threadIdx.x]);
}

// ---- scatter with wave-ballot aggregation (~8 atomics/wave) ---------------
__global__ __launch_bounds__(256) void scatter_kernel(const int* __restrict__ tok_e,
                                                      const int* __restrict__ counts,
                                                      int* __restrict__ cursors,
                                                      int* __restrict__ slot_token,
                                                      int* __restrict__ tok_slot) {
  int offs[NE + 1];
  load_offs(counts, offs);
  int t = blockIdx.x * 256 + threadIdx.x;
  int lane = threadIdx.x & 63;
#pragma unroll
  for (int j = 0; j < 2; j++) {
    int e = tok_e[t * 2 + j];
#pragma unroll
    for (int ee = 0; ee < NE; ee++) {
      unsigned long long m = __ballot(e == ee);
      if (e == ee) {
        int leader = __ffsll(m) - 1;
        int base = 0;
        if (lane == leader) base = atomicAdd(&cursors[ee], (int)__popcll(m));
        base = __shfl(base, leader);
        int pos = base + (int)__popcll(m & ((1ULL << lane) - 1ULL));
        int s = offs[ee] + pos;
        slot_token[s] = t;
        tok_slot[t * 2 + j] = s;
      }
    }
  }
}

// ===========================================================================
// GEMM core (m97): 128x128 tile, BK=64, 4 waves, global_load_lds width 16
// into LINEAR [128][64] bf16 LDS; XOR swizzle baked into the GLOBAL source
// chunk; ds_read un-swizzles (rule #21).  0 main-loop bank conflicts (r2).
// A-PANEL-MAJOR XCD swizzle (r6, verified: FETCH 592->460 MB, +MfmaUtil).
// ===========================================================================

// ---- GEMM1: h = gelu(x_gathered @ W1T[e] + b1[e]); h bf16 [SLOT_CAP][H] ---
__global__ __launch_bounds__(256) void gemm1_kernel(const unsigned short* __restrict__ Xb,
                                                    const unsigned short* __restrict__ W1T,
                                                    const float* __restrict__ b1,
                                                    const int* __restrict__ slot_token,
                                                    const int* __restrict__ counts,
                                                    unsigned short* __restrict__ Hbuf) {
  __shared__ __align__(16) unsigned short As[BM][BK];
  __shared__ __align__(16) unsigned short Bs[BN][BK];
  int offs[NE + 1];
  load_offs(counts, offs);
  const int GY = HDIM / BN;   // 32
  int lin = blockIdx.y * gridDim.x + blockIdx.x;
  int cpx = (TILES * GY) >> 3;
  int wk  = (lin & 7) * cpx + (lin >> 3);
  int bx = wk / GY, by = wk % GY;

  int row0 = bx * BM;
  if (row0 >= offs[NE]) return;
  int e = 0;
#pragma unroll
  for (int i = 1; i < NE; i++) if (row0 >= offs[i]) e = i;
  int n0  = by * BN;
  int tid  = threadIdx.x;
  int lane = tid & 63;
  int w    = tid >> 6;
  int wr = tid >> 7;
  int wc = (tid >> 6) & 1;

  int lr  = lane >> 3;
  int lcx = (lane & 7) ^ lr;
  const unsigned short* aG[4];
  const unsigned short* bG[4];
  unsigned short* aL[4];
  unsigned short* bL[4];
#pragma unroll
  for (int i = 0; i < 4; i++) {
    int r = w * 32 + i * 8;
    int tk = slot_token[row0 + r + lr];
    if (tk < 0) tk = 0;
    aG[i] = Xb + (size_t)tk * DIM + lcx * 8;
    bG[i] = W1T + ((size_t)e * HDIM + n0 + r + lr) * DIM + lcx * 8;
    aL[i] = &As[r][0];
    bL[i] = &Bs[r][0];
  }

  int frow = lane & 15;
  int hi   = lane >> 4;
  int kxs  = (hi * 8) ^ ((lane & 7) << 3);

  f32x4 acc[4][4];
#pragma unroll
  for (int m = 0; m < 4; m++)
#pragma unroll
    for (int n = 0; n < 4; n++) acc[m][n] = 0.f;

  for (int k0 = 0; k0 < DIM; k0 += BK) {
#pragma unroll
    for (int i = 0; i < 4; i++) gload_lds16(aG[i] + k0, aL[i]);
#pragma unroll
    for (int i = 0; i < 4; i++) gload_lds16(bG[i] + k0, bL[i]);
    __syncthreads();
#pragma unroll
    for (int kk = 0; kk < 2; kk++) {
      int col = (kk * 32) ^ kxs;
      u32x4 a[4], b[4];
#pragma unroll
      for (int m = 0; m < 4; m++)
        a[m] = *(const u32x4*)&As[wr * 64 + m * 16 + frow][col];
#pragma unroll
      for (int n = 0; n < 4; n++)
        b[n] = *(const u32x4*)&Bs[wc * 64 + n * 16 + frow][col];
#pragma unroll
      for (int m = 0; m < 4; m++)
#pragma unroll
        for (int n = 0; n < 4; n++)
          acc[m][n] = mfma_bf16_16x16x32(a[m], b[n], acc[m][n]);
    }
    __syncthreads();
  }

  // LDS-staged epilogue: gelu -> bf16 -> [32][136] LDS chunk -> 256B rows
  float bias[4];
#pragma unroll
  for (int n = 0; n < 4; n++) bias[n] = b1[e * HDIM + n0 + wc * 64 + n * 16 + frow];
  unsigned short (*E)[136] = (unsigned short (*)[136])(&As[0][0]);
#pragma unroll
  for (int c0 = 0; c0 < 128; c0 += 32) {
    if (wr == (c0 >> 6)) {
      int mbase = (c0 & 63) >> 4;
#pragma unroll
      for (int mm = 0; mm < 2; mm++) {
        int m = mbase + mm;
#pragma unroll
        for (int n = 0; n < 4; n++)
#pragma unroll
          for (int j = 0; j < 4; j++)
            E[mm * 16 + hi * 4 + j][wc * 64 + n * 16 + frow] =
                f2bf(gelu_fast(acc[m][n][j] + bias[n]));
      }
    }
    __syncthreads();
#pragma unroll
    for (int p = 0; p < 2; p++) {
      int r  = p * 16 + (tid >> 4);
      int cc = (tid & 15) * 8;
      u32x4 v = *(const u32x4*)&E[r][cc];
      *(u32x4*)(Hbuf + (size_t)(row0 + c0 + r) * HDIM + n0 + cc) = v;
    }
    __syncthreads();
  }
}

// ---- GEMM2: Ybuf[slot] = bf16(h @ W2T[e] + b2[e]), LDS-staged stores ------
__global__ __launch_bounds__(256) void gemm2_kernel(const unsigned short* __restrict__ Hbuf,
                                                    const unsigned short* __restrict__ W2T,
                                                    const float* __restrict__ b2,
                                                    const int* __restrict__ counts,
                                                    unsigned short* __restrict__ Ybuf) {
  __shared__ __align__(16) unsigned short As[BM][BK];
  __shared__ __align__(16) unsigned short Bs[BN][BK];
  int offs[NE + 1];
  load_offs(counts, offs);
  const int GY = DIM / BN;    // 8
  int lin = blockIdx.y * gridDim.x + blockIdx.x;
  int cpx = (TILES * GY) >> 3;
  int wk  = (lin & 7) * cpx + (lin >> 3);
  int bx = wk / GY, by = wk % GY;

  int row0 = bx * BM;
  if (row0 >= offs[NE]) return;
  int e = 0;
#pragma unroll
  for (int i = 1; i < NE; i++) if (row0 >= offs[i]) e = i;
  int n0  = by * BN;
  int tid  = threadIdx.x;
  int lane = tid & 63;
  int w    = tid >> 6;
  int wr = tid >> 7;
  int wc = (tid >> 6) & 1;

  int lr  = lane >> 3;
  int lcx = (lane & 7) ^ lr;
  const unsigned short* aG[4];
  const unsigned short* bG[4];
  unsigned short* aL[4];
  unsigned short* bL[4];
#pragma unroll
  for (int i = 0; i < 4; i++) {
    int r = w * 32 + i * 8;
    aG[i] = Hbuf + (size_t)(row0 + r + lr) * HDIM + lcx * 8;
    bG[i] = W2T + ((size_t)e * DIM + n0 + r + lr) * HDIM + lcx * 8;
    aL[i] = &As[r][0];
    bL[i] = &Bs[r][0];
  }

  int frow = lane & 15;
  int hi   = lane >> 4;
  int kxs  = (hi * 8) ^ ((lane & 7) << 3);

  f32x4 acc[4][4];
#pragma unroll
  for (int m = 0; m < 4; m++)
#pragma unroll
    for (int n = 0; n < 4; n++) acc[m][n] = 0.f;

  for (int k0 = 0; k0 < HDIM; k0 += BK) {
#pragma unroll
    for (int i = 0; i < 4; i++) gload_lds16(aG[i] + k0, aL[i]);
#pragma unroll
    for (int i = 0; i < 4; i++) gload_lds16(bG[i] + k0, bL[i]);
    __syncthreads();
#pragma unroll
    for (int kk = 0; kk < 2; kk++) {
      int col = (kk * 32) ^ kxs;
      u32x4 a[4], b[4];
#pragma unroll
      for (int m = 0; m < 4; m++)
        a[m] = *(const u32x4*)&As[wr * 64 + m * 16 + frow][col];
#pragma unroll
      for (int n = 0; n < 4; n++)
        b[n] = *(const u32x4*)&Bs[wc * 64 + n * 16 + frow][col];
#pragma unroll
      for (int m = 0; m < 4; m++)
#pragma unroll
        for (int n = 0; n < 4; n++)
          acc[m][n] = mfma_bf16_16x16x32(a[m], b[n], acc[m][n]);
    }
    __syncthreads();
  }

  // LDS-staged bf16 epilogue (same pattern as gemm1, no gelu)
  float bias[4];
#pragma unroll
  for (int n = 0; n < 4; n++) bias[n] = b2[e * DIM + n0 + wc * 64 + n * 16 + frow];
  unsigned short (*E)[136] = (unsigned short (*)[136])(&As[0][0]);
#pragma unroll
  for (int c0 = 0; c0 < 128; c0 += 32) {
    if (wr == (c0 >> 6)) {
      int mbase = (c0 & 63) >> 4;
#pragma unroll
      for (int mm = 0; mm < 2; mm++) {
        int m = mbase + mm;
#pragma unroll
        for (int n = 0; n < 4; n++)
#pragma unroll
          for (int j = 0; j < 4; j++)
            E[mm * 16 + hi * 4 + j][wc * 64 + n * 16 + frow] =
                f2bf(acc[m][n][j] + bias[n]);
      }
    }
    __syncthreads();
#pragma unroll
    for (int p = 0; p < 2; p++) {
      int r  = p * 16 + (tid >> 4);
      int cc = (tid & 15) * 8;
      u32x4 v = *(const u32x4*)&E[r][cc];
      *(u32x4*)(Ybuf + (size_t)(row0 + c0 + r) * DIM + n0 + cc) = v;
    }
    __syncthreads();
  }
}

// ---- combine: out[t] = w0*Y[s0] + w1*Y[s1]  (bf16 Y, 2 tokens/block) ------
__global__ __launch_bounds__(256) void combine_kernel(const unsigned short* __restrict__ Ybuf,
                                                      const int* __restrict__ tok_slot,
                                                      const float* __restrict__ tok_w,
                                                      float* __restrict__ out) {
  int t = blockIdx.x * 2 + (threadIdx.x >> 7);
  int c = (threadIdx.x & 127) * 8;
  int s0 = tok_slot[t * 2], s1 = tok_slot[t * 2 + 1];
  float w0 = tok_w[t * 2], w1 = tok_w[t * 2 + 1];
  u32x4 y0 = *(const u32x4*)(Ybuf + (size_t)s0 * DIM + c);
  u32x4 y1 = *(const u32x4*)(Ybuf + (size_t)s1 * DIM + c);
  float r[8];
#pragma unroll
  for (int k = 0; k < 4; k++) {
    union { unsigned int u; float f; } a0, b0, a1, b1;
    a0.u = y0[k] << 16; b0.u = y0[k] & 0xFFFF0000u;
    a1.u = y1[k] << 16; b1.u = y1[k] & 0xFFFF0000u;
    r[2 * k]     = w0 * a0.f + w1 * a1.f;
    r[2 * k + 1] = w0 * b0.f + w1 * b1.f;
  }
  float* o = out + (size_t)t * DIM + c;
  *(f32x4*)o       = *(f32x4*)&r[0];
  *(f32x4*)(o + 4) = *(f32x4*)&r[4];
}

extern "C" void kernel_launch(void* const* d_in, const int* in_sizes, int n_in,
                              void* d_out, int out_size, void* d_ws, size_t ws_size,
                              hipStream_t stream) {
  (void)in_sizes; (void)n_in; (void)out_size;
  const float* x  = (const float*)d_in[0];
  const float* Wg = (const float*)d_in[1];
  const float* W1 = (const float*)d_in[2];
  const float* b1 = (const float*)d_in[3];
  const float* W2 = (const float*)d_in[4];
  const float* b2 = (const float*)d_in[5];
  float* out = (float*)d_out;

  char* ws = (char*)d_ws;
  size_t off = 0;
  auto take = [&](size_t bytes) -> char* {
    char* p = ws + off;
    off += (bytes + 255) & ~(size_t)255;
    return p;
  };
  unsigned short* W1T  = (unsigned short*)take((size_t)NE * DIM * HDIM * 2);
  unsigned short* W2T  = (unsigned short*)take((size_t)NE * DIM * HDIM * 2);
  unsigned short* Xb   = (unsigned short*)take((size_t)T_TOK * DIM * 2);
  unsigned short* Hbuf = (unsigned short*)take((size_t)SLOT_CAP * HDIM * 2);
  unsigned short* Ybuf = (unsigned short*)take((size_t)SLOT_CAP * DIM * 2);
  int*   slot_token = (int*)take(SLOT_CAP * 4);
  int*   tok_e      = (int*)take(T_TOK * 2 * 4);
  float* tok_w      = (float*)take(T_TOK * 2 * 4);
  int*   tok_slot   = (int*)take(T_TOK * 2 * 4);
  int*   counts     = (int*)take(256);
  int*   cursors    = (int*)take(256);

  if (off > ws_size) {
    hipMemsetAsync(d_out, 0, (size_t)out_size * 4, stream);
    return;
  }

  hipMemsetAsync(counts, 0, 256, stream);
  hipMemsetAsync(cursors, 0, 256, stream);
  hipMemsetAsync(slot_token, 0xFF, SLOT_CAP * 4, stream);

  routing_kernel<<<T_TOK / 4, 256, 0, stream>>>(x, Wg, tok_e, tok_w, Xb, counts);
  scatter_kernel<<<T_TOK / 256, 256, 0, stream>>>(tok_e, counts, cursors, slot_token, tok_slot);
  transpose_bf16_kernel<<<dim3(HDIM / 64, DIM / 64, NE), 256, 0, stream>>>(W1, W1T, DIM, HDIM);
  transpose_bf16_kernel<<<dim3(DIM / 64, HDIM / 64, NE), 256, 0, stream>>>(W2, W2T, HDIM, DIM);
  gemm1_kernel<<<dim3(TILES, HDIM / BN), 256, 0, stream>>>(Xb, W1T, b1, slot_token, counts, Hbuf);
  gemm2_kernel<<<dim3(TILES, DIM / BN), 256, 0, stream>>>(Hbuf, W2T, b2, counts, Ybuf);
  combine_kernel<<<T_TOK / 2, 256, 0, stream>>>(Ybuf, tok_slot, tok_w, out);
}

// Round 8
// 497.770 us; speedup vs baseline: 1.6075x; 1.0674x over previous
//
#include <hip/hip_runtime.h>

#define T_TOK 8192
#define DIM   1024
#define HDIM  4096
#define NE    8
#define BK    64
#define BM    128
#define BN    128
#define SLOT_CAP (T_TOK * 2 + NE * BM)   // 17408 = 136*128
#define TILES (SLOT_CAP / BM)            // 136

typedef float        f32x4 __attribute__((ext_vector_type(4)));
typedef unsigned int u32x4 __attribute__((ext_vector_type(4)));

__device__ inline unsigned short f2bf(float f) {
  union { float f; unsigned int u; } a; a.f = f;
  unsigned int u = a.u;
  unsigned int r = (u + 0x7FFFu + ((u >> 16) & 1u)) >> 16;  // RNE
  return (unsigned short)r;
}

__device__ inline f32x4 mfma_bf16_16x16x32(u32x4 a, u32x4 b, f32x4 c) {
  asm("v_mfma_f32_16x16x32_bf16 %0, %1, %2, %0" : "+v"(c) : "v"(a), "v"(b));
  return c;
}

__device__ inline void gload_lds16(const void* g, void* l) {
  __builtin_amdgcn_global_load_lds(
      (const __attribute__((address_space(1))) void*)g,
      (__attribute__((address_space(3))) void*)l, 16, 0, 0);
}

// gelu(v) = v * sigmoid(2*c*(v + 0.044715 v^3))  (tanh-form identity)
__device__ inline float gelu_fast(float v) {
  const float c2 = 1.5957691216057308f;   // 2*sqrt(2/pi)
  float z = c2 * (v + 0.044715f * v * v * v);
  return v / (1.0f + __expf(-z));
}

// padded (128-aligned) expert segment prefix, recomputed locally
__device__ inline void load_offs(const int* __restrict__ counts, int* offs) {
  offs[0] = 0;
#pragma unroll
  for (int e = 0; e < NE; e++)
    offs[e + 1] = offs[e] + ((counts[e] + BM - 1) / BM) * BM;
}

// ===========================================================================
// prep: ONE kernel = routing (blocks 0..2047) + transpose W1 (2048..10239)
//       + transpose W2 (10240..18431).  All three are mutually independent;
//       merging removes ~2 launch serializations (~25-30 us on one stream).
// ===========================================================================
__device__ void transpose_body(const float* __restrict__ src,
                               unsigned short* __restrict__ dst,
                               int R, int C, int e, int c0, int r0,
                               float (*tile)[65]) {
  int c  = threadIdx.x & 63, r4 = threadIdx.x >> 6;
  const float* s = src + (size_t)e * R * C;
#pragma unroll
  for (int i = 0; i < 16; i++) {
    int r = r4 + i * 4;
    tile[r][c] = s[(size_t)(r0 + r) * C + (c0 + c)];
  }
  __syncthreads();
  unsigned short* d = dst + (size_t)e * R * C;
  int rbase = (threadIdx.x & 7) * 8;
#pragma unroll
  for (int g = 0; g < 2; g++) {
    int cc = (threadIdx.x >> 3) + g * 32;
    u32x4 v;
#pragma unroll
    for (int k = 0; k < 4; k++)
      v[k] = (unsigned int)f2bf(tile[rbase + 2 * k][cc])
           | ((unsigned int)f2bf(tile[rbase + 2 * k + 1][cc]) << 16);
    *(u32x4*)(d + (size_t)(c0 + cc) * R + (r0 + rbase)) = v;
  }
}

__global__ __launch_bounds__(256) void prep_kernel(const float* __restrict__ x,
                                                   const float* __restrict__ Wg,
                                                   int* __restrict__ tok_e,
                                                   float* __restrict__ tok_w,
                                                   unsigned short* __restrict__ xb,
                                                   int* __restrict__ counts,
                                                   const float* __restrict__ W1,
                                                   unsigned short* __restrict__ W1T,
                                                   const float* __restrict__ W2,
                                                   unsigned short* __restrict__ W2T) {
  __shared__ float tile[64][65];
  __shared__ int h[NE];
  int bid = blockIdx.x;
  if (bid < T_TOK / 4) {
    // ---- routing + fused x->bf16 convert + histogram ----
    if (threadIdx.x < NE) h[threadIdx.x] = 0;
    __syncthreads();
    int tok  = bid * 4 + (threadIdx.x >> 6);
    int lane = threadIdx.x & 63;
    const float* xr = x + (size_t)tok * DIM;
    float acc[NE];
#pragma unroll
    for (int e = 0; e < NE; e++) acc[e] = 0.f;
    for (int d = lane; d < DIM; d += 64) {
      float xv = xr[d];
      const float* wr = Wg + d * NE;
#pragma unroll
      for (int e = 0; e < NE; e++) acc[e] += xv * wr[e];
    }
#pragma unroll
    for (int e = 0; e < NE; e++) {
#pragma unroll
      for (int off = 32; off > 0; off >>= 1) acc[e] += __shfl_xor(acc[e], off);
    }
    if (lane == 0) {
      int i0 = 0;
#pragma unroll
      for (int e = 1; e < NE; e++) if (acc[e] > acc[i0]) i0 = e;
      int i1 = (i0 == 0) ? 1 : 0;
#pragma unroll
      for (int e = 0; e < NE; e++) if (e != i0 && acc[e] > acc[i1]) i1 = e;
      float w0 = 1.0f / (1.0f + expf(acc[i1] - acc[i0]));
      tok_e[tok * 2]     = i0;
      tok_e[tok * 2 + 1] = i1;
      tok_w[tok * 2]     = w0;
      tok_w[tok * 2 + 1] = 1.0f - w0;
      atomicAdd(&h[i0], 1);
      atomicAdd(&h[i1], 1);
    }
    unsigned short* xo = xb + (size_t)tok * DIM;
#pragma unroll
    for (int i = 0; i < 4; i++) {
      f32x4 v = *(const f32x4*)(xr + lane * 16 + i * 4);
      unsigned long long p = (unsigned long long)f2bf(v[0])
                           | ((unsigned long long)f2bf(v[1]) << 16)
                           | ((unsigned long long)f2bf(v[2]) << 32)
                           | ((unsigned long long)f2bf(v[3]) << 48);
      *(unsigned long long*)(xo + lane * 16 + i * 4) = p;
    }
    __syncthreads();
    if (threadIdx.x < NE) atomicAdd(&counts[threadIdx.x], h[threadIdx.x]);
  } else if (bid < T_TOK / 4 + 8192) {
    // ---- W1 [E][1024][4096] -> W1T [E][4096][1024] bf16 ----
    int idx = bid - T_TOK / 4;
    transpose_body(W1, W1T, DIM, HDIM, idx >> 10, (idx & 63) * 64,
                   ((idx >> 6) & 15) * 64, tile);
  } else {
    // ---- W2 [E][4096][1024] -> W2T [E][1024][4096] bf16 ----
    int idx = bid - T_TOK / 4 - 8192;
    transpose_body(W2, W2T, HDIM, DIM, idx >> 10, (idx & 15) * 64,
                   ((idx >> 4) & 63) * 64, tile);
  }
}

// ---- scatter (wave-ballot aggregated) + padding init (block 0) ------------
__global__ __launch_bounds__(256) void scatter_kernel(const int* __restrict__ tok_e,
                                                      const int* __restrict__ counts,
                                                      int* __restrict__ cursors,
                                                      int* __restrict__ slot_token,
                                                      int* __restrict__ tok_slot) {
  int offs[NE + 1];
  load_offs(counts, offs);
  if (blockIdx.x == 0) {
#pragma unroll
    for (int e = 0; e < NE; e++)
      for (int s = offs[e] + counts[e] + threadIdx.x; s < offs[e + 1]; s += 256)
        slot_token[s] = -1;
  }
  int t = blockIdx.x * 256 + threadIdx.x;
  int lane = threadIdx.x & 63;
#pragma unroll
  for (int j = 0; j < 2; j++) {
    int e = tok_e[t * 2 + j];
#pragma unroll
    for (int ee = 0; ee < NE; ee++) {
      unsigned long long m = __ballot(e == ee);
      if (e == ee) {
        int leader = __ffsll(m) - 1;
        int base = 0;
        if (lane == leader) base = atomicAdd(&cursors[ee], (int)__popcll(m));
        base = __shfl(base, leader);
        int pos = base + (int)__popcll(m & ((1ULL << lane) - 1ULL));
        int s = offs[ee] + pos;
        slot_token[s] = t;
        tok_slot[t * 2 + j] = s;
      }
    }
  }
}

// ===========================================================================
// GEMM core (m97): 128x128 tile, BK=64, 4 waves, global_load_lds width 16
// into LINEAR [128][64] bf16 LDS; XOR swizzle baked into the GLOBAL source
// chunk; ds_read un-swizzles (rule #21).  0 main-loop bank conflicts (r2).
// A-PANEL-MAJOR XCD swizzle (r6 verified).
// ===========================================================================

// ---- GEMM1: h = gelu(x_gathered @ W1T[e] + b1[e]); h bf16 [SLOT_CAP][H] ---
__global__ __launch_bounds__(256) void gemm1_kernel(const unsigned short* __restrict__ Xb,
                                                    const unsigned short* __restrict__ W1T,
                                                    const float* __restrict__ b1,
                                                    const int* __restrict__ slot_token,
                                                    const int* __restrict__ counts,
                                                    unsigned short* __restrict__ Hbuf) {
  __shared__ __align__(16) unsigned short As[BM][BK];
  __shared__ __align__(16) unsigned short Bs[BN][BK];
  int offs[NE + 1];
  load_offs(counts, offs);
  const int GY = HDIM / BN;   // 32
  int lin = blockIdx.y * gridDim.x + blockIdx.x;
  int cpx = (TILES * GY) >> 3;
  int wk  = (lin & 7) * cpx + (lin >> 3);
  int bx = wk / GY, by = wk % GY;

  int row0 = bx * BM;
  if (row0 >= offs[NE]) return;
  int e = 0;
#pragma unroll
  for (int i = 1; i < NE; i++) if (row0 >= offs[i]) e = i;
  int n0  = by * BN;
  int tid  = threadIdx.x;
  int lane = tid & 63;
  int w    = tid >> 6;
  int wr = tid >> 7;
  int wc = (tid >> 6) & 1;

  int lr  = lane >> 3;
  int lcx = (lane & 7) ^ lr;
  const unsigned short* aG[4];
  const unsigned short* bG[4];
  unsigned short* aL[4];
  unsigned short* bL[4];
#pragma unroll
  for (int i = 0; i < 4; i++) {
    int r = w * 32 + i * 8;
    int tk = slot_token[row0 + r + lr];
    if (tk < 0) tk = 0;
    aG[i] = Xb + (size_t)tk * DIM + lcx * 8;
    bG[i] = W1T + ((size_t)e * HDIM + n0 + r + lr) * DIM + lcx * 8;
    aL[i] = &As[r][0];
    bL[i] = &Bs[r][0];
  }

  int frow = lane & 15;
  int hi   = lane >> 4;
  int kxs  = (hi * 8) ^ ((lane & 7) << 3);

  f32x4 acc[4][4];
#pragma unroll
  for (int m = 0; m < 4; m++)
#pragma unroll
    for (int n = 0; n < 4; n++) acc[m][n] = 0.f;

  for (int k0 = 0; k0 < DIM; k0 += BK) {
#pragma unroll
    for (int i = 0; i < 4; i++) gload_lds16(aG[i] + k0, aL[i]);
#pragma unroll
    for (int i = 0; i < 4; i++) gload_lds16(bG[i] + k0, bL[i]);
    __syncthreads();
#pragma unroll
    for (int kk = 0; kk < 2; kk++) {
      int col = (kk * 32) ^ kxs;
      u32x4 a[4], b[4];
#pragma unroll
      for (int m = 0; m < 4; m++)
        a[m] = *(const u32x4*)&As[wr * 64 + m * 16 + frow][col];
#pragma unroll
      for (int n = 0; n < 4; n++)
        b[n] = *(const u32x4*)&Bs[wc * 64 + n * 16 + frow][col];
#pragma unroll
      for (int m = 0; m < 4; m++)
#pragma unroll
        for (int n = 0; n < 4; n++)
          acc[m][n] = mfma_bf16_16x16x32(a[m], b[n], acc[m][n]);
    }
    __syncthreads();
  }

  // LDS-staged epilogue: gelu -> bf16 -> [32][136] LDS chunk -> 256B rows
  float bias[4];
#pragma unroll
  for (int n = 0; n < 4; n++) bias[n] = b1[e * HDIM + n0 + wc * 64 + n * 16 + frow];
  unsigned short (*E)[136] = (unsigned short (*)[136])(&As[0][0]);
#pragma unroll
  for (int c0 = 0; c0 < 128; c0 += 32) {
    if (wr == (c0 >> 6)) {
      int mbase = (c0 & 63) >> 4;
#pragma unroll
      for (int mm = 0; mm < 2; mm++) {
        int m = mbase + mm;
#pragma unroll
        for (int n = 0; n < 4; n++)
#pragma unroll
          for (int j = 0; j < 4; j++)
            E[mm * 16 + hi * 4 + j][wc * 64 + n * 16 + frow] =
                f2bf(gelu_fast(acc[m][n][j] + bias[n]));
      }
    }
    __syncthreads();
#pragma unroll
    for (int p = 0; p < 2; p++) {
      int r  = p * 16 + (tid >> 4);
      int cc = (tid & 15) * 8;
      u32x4 v = *(const u32x4*)&E[r][cc];
      *(u32x4*)(Hbuf + (size_t)(row0 + c0 + r) * HDIM + n0 + cc) = v;
    }
    __syncthreads();
  }
}

// ---- GEMM2 split-K=2 (two-pass, no atomics): Ybuf[sp][slot] partials ------
// 2176 blocks fixes the 1088-block tail (~66% -> ~88% dispatch utilization).
__global__ __launch_bounds__(256) void gemm2_kernel(const unsigned short* __restrict__ Hbuf,
                                                    const unsigned short* __restrict__ W2T,
                                                    const float* __restrict__ b2,
                                                    const int* __restrict__ counts,
                                                    unsigned short* __restrict__ Ybuf) {
  __shared__ __align__(16) unsigned short As[BM][BK];
  __shared__ __align__(16) unsigned short Bs[BN][BK];
  int offs[NE + 1];
  load_offs(counts, offs);
  const int GY2 = (DIM / BN) * 2;   // 16: {8 n-tiles} x {2 K-splits}
  int lin = blockIdx.y * gridDim.x + blockIdx.x;
  int cpx = (TILES * GY2) >> 3;
  int wk  = (lin & 7) * cpx + (lin >> 3);
  int bx = wk / GY2;
  int rem = wk % GY2;
  int by = rem & 7, sp = rem >> 3;   // sp slowest: 8 consecutive share A K-half
  int kbase = sp * (HDIM / 2);

  int row0 = bx * BM;
  if (row0 >= offs[NE]) return;
  int e = 0;
#pragma unroll
  for (int i = 1; i < NE; i++) if (row0 >= offs[i]) e = i;
  int n0  = by * BN;
  int tid  = threadIdx.x;
  int lane = tid & 63;
  int w    = tid >> 6;
  int wr = tid >> 7;
  int wc = (tid >> 6) & 1;

  int lr  = lane >> 3;
  int lcx = (lane & 7) ^ lr;
  const unsigned short* aG[4];
  const unsigned short* bG[4];
  unsigned short* aL[4];
  unsigned short* bL[4];
#pragma unroll
  for (int i = 0; i < 4; i++) {
    int r = w * 32 + i * 8;
    aG[i] = Hbuf + (size_t)(row0 + r + lr) * HDIM + kbase + lcx * 8;
    bG[i] = W2T + ((size_t)e * DIM + n0 + r + lr) * HDIM + kbase + lcx * 8;
    aL[i] = &As[r][0];
    bL[i] = &Bs[r][0];
  }

  int frow = lane & 15;
  int hi   = lane >> 4;
  int kxs  = (hi * 8) ^ ((lane & 7) << 3);

  f32x4 acc[4][4];
#pragma unroll
  for (int m = 0; m < 4; m++)
#pragma unroll
    for (int n = 0; n < 4; n++) acc[m][n] = 0.f;

  for (int k0 = 0; k0 < HDIM / 2; k0 += BK) {
#pragma unroll
    for (int i = 0; i < 4; i++) gload_lds16(aG[i] + k0, aL[i]);
#pragma unroll
    for (int i = 0; i < 4; i++) gload_lds16(bG[i] + k0, bL[i]);
    __syncthreads();
#pragma unroll
    for (int kk = 0; kk < 2; kk++) {
      int col = (kk * 32) ^ kxs;
      u32x4 a[4], b[4];
#pragma unroll
      for (int m = 0; m < 4; m++)
        a[m] = *(const u32x4*)&As[wr * 64 + m * 16 + frow][col];
#pragma unroll
      for (int n = 0; n < 4; n++)
        b[n] = *(const u32x4*)&Bs[wc * 64 + n * 16 + frow][col];
#pragma unroll
      for (int m = 0; m < 4; m++)
#pragma unroll
        for (int n = 0; n < 4; n++)
          acc[m][n] = mfma_bf16_16x16x32(a[m], b[n], acc[m][n]);
    }
    __syncthreads();
  }

  // LDS-staged bf16 epilogue; bias added on split 1 only
  float bias[4];
#pragma unroll
  for (int n = 0; n < 4; n++)
    bias[n] = sp ? b2[e * DIM + n0 + wc * 64 + n * 16 + frow] : 0.f;
  unsigned short* Yp = Ybuf + (size_t)sp * SLOT_CAP * DIM;
  unsigned short (*E)[136] = (unsigned short (*)[136])(&As[0][0]);
#pragma unroll
  for (int c0 = 0; c0 < 128; c0 += 32) {
    if (wr == (c0 >> 6)) {
      int mbase = (c0 & 63) >> 4;
#pragma unroll
      for (int mm = 0; mm < 2; mm++) {
        int m = mbase + mm;
#pragma unroll
        for (int n = 0; n < 4; n++)
#pragma unroll
          for (int j = 0; j < 4; j++)
            E[mm * 16 + hi * 4 + j][wc * 64 + n * 16 + frow] =
                f2bf(acc[m][n][j] + bias[n]);
      }
    }
    __syncthreads();
#pragma unroll
    for (int p = 0; p < 2; p++) {
      int r  = p * 16 + (tid >> 4);
      int cc = (tid & 15) * 8;
      u32x4 v = *(const u32x4*)&E[r][cc];
      *(u32x4*)(Yp + (size_t)(row0 + c0 + r) * DIM + n0 + cc) = v;
    }
    __syncthreads();
  }
}

// ---- combine: out[t] = w0*(Y0[s0]+Y1[s0]) + w1*(Y0[s1]+Y1[s1]) ------------
__global__ __launch_bounds__(256) void combine_kernel(const unsigned short* __restrict__ Ybuf,
                                                      const int* __restrict__ tok_slot,
                                                      const float* __restrict__ tok_w,
                                                      float* __restrict__ out) {
  int t = blockIdx.x * 2 + (threadIdx.x >> 7);
  int c = (threadIdx.x & 127) * 8;
  int s0 = tok_slot[t * 2], s1 = tok_slot[t * 2 + 1];
  float w0 = tok_w[t * 2], w1 = tok_w[t * 2 + 1];
  const unsigned short* Y1 = Ybuf + (size_t)SLOT_CAP * DIM;
  u32x4 p0 = *(const u32x4*)(Ybuf + (size_t)s0 * DIM + c);
  u32x4 p1 = *(const u32x4*)(Y1   + (size_t)s0 * DIM + c);
  u32x4 q0 = *(const u32x4*)(Ybuf + (size_t)s1 * DIM + c);
  u32x4 q1 = *(const u32x4*)(Y1   + (size_t)s1 * DIM + c);
  float r[8];
#pragma unroll
  for (int k = 0; k < 4; k++) {
    union { unsigned int u; float f; } a;
#pragma unroll
    for (int hl = 0; hl < 2; hl++) {
      unsigned int sh = hl ? 0 : 16;
      unsigned int msk = hl ? 0xFFFF0000u : 0xFFFFFFFFu;
      a.u = hl ? (p0[k] & 0xFFFF0000u) : (p0[k] << 16); float vp0 = a.f;
      a.u = hl ? (p1[k] & 0xFFFF0000u) : (p1[k] << 16); float vp1 = a.f;
      a.u = hl ? (q0[k] & 0xFFFF0000u) : (q0[k] << 16); float vq0 = a.f;
      a.u = hl ? (q1[k] & 0xFFFF0000u) : (q1[k] << 16); float vq1 = a.f;
      (void)sh; (void)msk;
      r[2 * k + hl] = w0 * (vp0 + vp1) + w1 * (vq0 + vq1);
    }
  }
  float* o = out + (size_t)t * DIM + c;
  *(f32x4*)o       = *(f32x4*)&r[0];
  *(f32x4*)(o + 4) = *(f32x4*)&r[4];
}

extern "C" void kernel_launch(void* const* d_in, const int* in_sizes, int n_in,
                              void* d_out, int out_size, void* d_ws, size_t ws_size,
                              hipStream_t stream) {
  (void)in_sizes; (void)n_in; (void)out_size;
  const float* x  = (const float*)d_in[0];
  const float* Wg = (const float*)d_in[1];
  const float* W1 = (const float*)d_in[2];
  const float* b1 = (const float*)d_in[3];
  const float* W2 = (const float*)d_in[4];
  const float* b2 = (const float*)d_in[5];
  float* out = (float*)d_out;

  char* ws = (char*)d_ws;
  size_t off = 0;
  auto take = [&](size_t bytes) -> char* {
    char* p = ws + off;
    off += (bytes + 255) & ~(size_t)255;
    return p;
  };
  unsigned short* W1T  = (unsigned short*)take((size_t)NE * DIM * HDIM * 2);
  unsigned short* W2T  = (unsigned short*)take((size_t)NE * DIM * HDIM * 2);
  unsigned short* Xb   = (unsigned short*)take((size_t)T_TOK * DIM * 2);
  unsigned short* Hbuf = (unsigned short*)take((size_t)SLOT_CAP * HDIM * 2);
  unsigned short* Ybuf = (unsigned short*)take((size_t)2 * SLOT_CAP * DIM * 2);
  int*   slot_token = (int*)take(SLOT_CAP * 4);
  int*   tok_e      = (int*)take(T_TOK * 2 * 4);
  float* tok_w      = (float*)take(T_TOK * 2 * 4);
  int*   tok_slot   = (int*)take(T_TOK * 2 * 4);
  int*   cnt_cur    = (int*)take(256);
  int*   counts  = cnt_cur;        // 8 ints
  int*   cursors = cnt_cur + 32;   // 8 ints (128B-separated)

  if (off > ws_size) {
    hipMemsetAsync(d_out, 0, (size_t)out_size * 4, stream);
    return;
  }

  hipMemsetAsync(cnt_cur, 0, 256, stream);
  prep_kernel<<<T_TOK / 4 + 16384, 256, 0, stream>>>(x, Wg, tok_e, tok_w, Xb,
                                                     counts, W1, W1T, W2, W2T);
  scatter_kernel<<<T_TOK / 256, 256, 0, stream>>>(tok_e, counts, cursors,
                                                  slot_token, tok_slot);
  gemm1_kernel<<<dim3(TILES, HDIM / BN), 256, 0, stream>>>(Xb, W1T, b1,
                                                           slot_token, counts, Hbuf);
  gemm2_kernel<<<dim3(TILES, 16), 256, 0, stream>>>(Hbuf, W2T, b2, counts, Ybuf);
  combine_kernel<<<T_TOK / 2, 256, 0, stream>>>(Ybuf, tok_slot, tok_w, out);
}

// Round 9
// 482.077 us; speedup vs baseline: 1.6598x; 1.0326x over previous
//
#include <hip/hip_runtime.h>

#define T_TOK 8192
#define DIM   1024
#define HDIM  4096
#define NE    8
#define BK    64
#define BM    128
#define BN    128
#define SLOT_CAP (T_TOK * 2 + NE * BM)   // 17408 = 136*128
#define TILES (SLOT_CAP / BM)            // 136
#define G1BLKS (TILES * (HDIM / BN))     // 4352 gemm1 tile-blocks
#define W2BLKS ((HDIM / 64) * (DIM / 64) * NE)  // 8192 transpose blocks

typedef float        f32x4 __attribute__((ext_vector_type(4)));
typedef unsigned int u32x4 __attribute__((ext_vector_type(4)));

__device__ inline unsigned short f2bf(float f) {
  union { float f; unsigned int u; } a; a.f = f;
  unsigned int u = a.u;
  unsigned int r = (u + 0x7FFFu + ((u >> 16) & 1u)) >> 16;  // RNE
  return (unsigned short)r;
}

__device__ inline f32x4 mfma_bf16_16x16x32(u32x4 a, u32x4 b, f32x4 c) {
  asm("v_mfma_f32_16x16x32_bf16 %0, %1, %2, %0" : "+v"(c) : "v"(a), "v"(b));
  return c;
}

__device__ inline void gload_lds16(const void* g, void* l) {
  __builtin_amdgcn_global_load_lds(
      (const __attribute__((address_space(1))) void*)g,
      (__attribute__((address_space(3))) void*)l, 16, 0, 0);
}

// gelu(v) = v * sigmoid(2*c*(v + 0.044715 v^3))  (tanh-form identity)
__device__ inline float gelu_fast(float v) {
  const float c2 = 1.5957691216057308f;   // 2*sqrt(2/pi)
  float z = c2 * (v + 0.044715f * v * v * v);
  return v / (1.0f + __expf(-z));
}

// padded (128-aligned) expert segment prefix, recomputed locally
__device__ inline void load_offs(const int* __restrict__ counts, int* offs) {
  offs[0] = 0;
#pragma unroll
  for (int e = 0; e < NE; e++)
    offs[e + 1] = offs[e] + ((counts[e] + BM - 1) / BM) * BM;
}

// ---- 64x64 transpose tile body: src fp32 [E][R][C] -> dst bf16 [E][C][R] --
__device__ void transpose_body(const float* __restrict__ src,
                               unsigned short* __restrict__ dst,
                               int R, int C, int e, int c0, int r0,
                               float (*tile)[65]) {
  int c  = threadIdx.x & 63, r4 = threadIdx.x >> 6;
  const float* s = src + (size_t)e * R * C;
#pragma unroll
  for (int i = 0; i < 16; i++) {
    int r = r4 + i * 4;
    tile[r][c] = s[(size_t)(r0 + r) * C + (c0 + c)];
  }
  __syncthreads();
  unsigned short* d = dst + (size_t)e * R * C;
  int rbase = (threadIdx.x & 7) * 8;
#pragma unroll
  for (int g = 0; g < 2; g++) {
    int cc = (threadIdx.x >> 3) + g * 32;
    u32x4 v;
#pragma unroll
    for (int k = 0; k < 4; k++)
      v[k] = (unsigned int)f2bf(tile[rbase + 2 * k][cc])
           | ((unsigned int)f2bf(tile[rbase + 2 * k + 1][cc]) << 16);
    *(u32x4*)(d + (size_t)(c0 + cc) * R + (r0 + rbase)) = v;
  }
}

// ===========================================================================
// prep: routing (blocks 0..2047) + transpose W1 (2048..10239).
// W2's transpose moved into gemm1's grid tail (backfills gemm1's dispatch
// tail using idle HBM BW; gemm1 runs at only ~39% BW).
// ===========================================================================
__global__ __launch_bounds__(256) void prep_kernel(const float* __restrict__ x,
                                                   const float* __restrict__ Wg,
                                                   int* __restrict__ tok_e,
                                                   float* __restrict__ tok_w,
                                                   unsigned short* __restrict__ xb,
                                                   int* __restrict__ counts,
                                                   const float* __restrict__ W1,
                                                   unsigned short* __restrict__ W1T) {
  __shared__ float tile[64][65];
  __shared__ int h[NE];
  int bid = blockIdx.x;
  if (bid < T_TOK / 4) {
    // ---- routing + fused x->bf16 convert + histogram ----
    if (threadIdx.x < NE) h[threadIdx.x] = 0;
    __syncthreads();
    int tok  = bid * 4 + (threadIdx.x >> 6);
    int lane = threadIdx.x & 63;
    const float* xr = x + (size_t)tok * DIM;
    float acc[NE];
#pragma unroll
    for (int e = 0; e < NE; e++) acc[e] = 0.f;
    for (int d = lane; d < DIM; d += 64) {
      float xv = xr[d];
      const float* wr = Wg + d * NE;
#pragma unroll
      for (int e = 0; e < NE; e++) acc[e] += xv * wr[e];
    }
#pragma unroll
    for (int e = 0; e < NE; e++) {
#pragma unroll
      for (int off = 32; off > 0; off >>= 1) acc[e] += __shfl_xor(acc[e], off);
    }
    if (lane == 0) {
      int i0 = 0;
#pragma unroll
      for (int e = 1; e < NE; e++) if (acc[e] > acc[i0]) i0 = e;
      int i1 = (i0 == 0) ? 1 : 0;
#pragma unroll
      for (int e = 0; e < NE; e++) if (e != i0 && acc[e] > acc[i1]) i1 = e;
      float w0 = 1.0f / (1.0f + expf(acc[i1] - acc[i0]));
      tok_e[tok * 2]     = i0;
      tok_e[tok * 2 + 1] = i1;
      tok_w[tok * 2]     = w0;
      tok_w[tok * 2 + 1] = 1.0f - w0;
      atomicAdd(&h[i0], 1);
      atomicAdd(&h[i1], 1);
    }
    unsigned short* xo = xb + (size_t)tok * DIM;
#pragma unroll
    for (int i = 0; i < 4; i++) {
      f32x4 v = *(const f32x4*)(xr + lane * 16 + i * 4);
      unsigned long long p = (unsigned long long)f2bf(v[0])
                           | ((unsigned long long)f2bf(v[1]) << 16)
                           | ((unsigned long long)f2bf(v[2]) << 32)
                           | ((unsigned long long)f2bf(v[3]) << 48);
      *(unsigned long long*)(xo + lane * 16 + i * 4) = p;
    }
    __syncthreads();
    if (threadIdx.x < NE) atomicAdd(&counts[threadIdx.x], h[threadIdx.x]);
  } else {
    // ---- W1 [E][1024][4096] -> W1T [E][4096][1024] bf16 ----
    int idx = bid - T_TOK / 4;
    transpose_body(W1, W1T, DIM, HDIM, idx >> 10, (idx & 63) * 64,
                   ((idx >> 6) & 15) * 64, tile);
  }
}

// ---- scatter (wave-ballot aggregated) + padding init (block 0) ------------
__global__ __launch_bounds__(256) void scatter_kernel(const int* __restrict__ tok_e,
                                                      const int* __restrict__ counts,
                                                      int* __restrict__ cursors,
                                                      int* __restrict__ slot_token,
                                                      int* __restrict__ tok_slot) {
  int offs[NE + 1];
  load_offs(counts, offs);
  if (blockIdx.x == 0) {
#pragma unroll
    for (int e = 0; e < NE; e++)
      for (int s = offs[e] + counts[e] + threadIdx.x; s < offs[e + 1]; s += 256)
        slot_token[s] = -1;
  }
  int t = blockIdx.x * 256 + threadIdx.x;
  int lane = threadIdx.x & 63;
#pragma unroll
  for (int j = 0; j < 2; j++) {
    int e = tok_e[t * 2 + j];
#pragma unroll
    for (int ee = 0; ee < NE; ee++) {
      unsigned long long m = __ballot(e == ee);
      if (e == ee) {
        int leader = __ffsll(m) - 1;
        int base = 0;
        if (lane == leader) base = atomicAdd(&cursors[ee], (int)__popcll(m));
        base = __shfl(base, leader);
        int pos = base + (int)__popcll(m & ((1ULL << lane) - 1ULL));
        int s = offs[ee] + pos;
        slot_token[s] = t;
        tok_slot[t * 2 + j] = s;
      }
    }
  }
}

// ===========================================================================
// GEMM core (m97): 128x128 tile, BK=64, 4 waves, global_load_lds width 16
// into LINEAR [128][64] bf16 LDS; XOR swizzle baked into the GLOBAL source
// chunk; ds_read un-swizzles (rule #21).  0 main-loop bank conflicts (r2).
// A-PANEL-MAJOR XCD swizzle (r6 verified).
// gemm1 grid tail (blocks >= G1BLKS): W2 transpose backfill — independent
// work (gemm1 never touches W2/W2T; gemm2 launches after kernel completes).
// ===========================================================================

// ---- GEMM1 + W2-transpose backfill ----------------------------------------
__global__ __launch_bounds__(256) void gemm1_kernel(const unsigned short* __restrict__ Xb,
                                                    const unsigned short* __restrict__ W1T,
                                                    const float* __restrict__ b1,
                                                    const int* __restrict__ slot_token,
                                                    const int* __restrict__ counts,
                                                    unsigned short* __restrict__ Hbuf,
                                                    const float* __restrict__ W2,
                                                    unsigned short* __restrict__ W2T) {
  __shared__ __align__(16) unsigned short SMEM[2 * BM * BK];   // 32 KB overlay
  if (blockIdx.x >= G1BLKS) {
    // ---- W2 [E][4096][1024] -> W2T [E][1024][4096] bf16 ----
    int idx = blockIdx.x - G1BLKS;
    transpose_body(W2, W2T, HDIM, DIM, idx >> 10, (idx & 15) * 64,
                   ((idx >> 4) & 63) * 64, (float (*)[65])SMEM);
    return;
  }
  unsigned short (*As)[BK] = (unsigned short (*)[BK])SMEM;
  unsigned short (*Bs)[BK] = (unsigned short (*)[BK])(SMEM + BM * BK);
  int offs[NE + 1];
  load_offs(counts, offs);
  const int GY = HDIM / BN;   // 32
  int lin = blockIdx.x;
  int cpx = G1BLKS >> 3;
  int wk  = (lin & 7) * cpx + (lin >> 3);
  int bx = wk / GY, by = wk % GY;

  int row0 = bx * BM;
  if (row0 >= offs[NE]) return;
  int e = 0;
#pragma unroll
  for (int i = 1; i < NE; i++) if (row0 >= offs[i]) e = i;
  int n0  = by * BN;
  int tid  = threadIdx.x;
  int lane = tid & 63;
  int w    = tid >> 6;
  int wr = tid >> 7;
  int wc = (tid >> 6) & 1;

  int lr  = lane >> 3;
  int lcx = (lane & 7) ^ lr;
  const unsigned short* aG[4];
  const unsigned short* bG[4];
  unsigned short* aL[4];
  unsigned short* bL[4];
#pragma unroll
  for (int i = 0; i < 4; i++) {
    int r = w * 32 + i * 8;
    int tk = slot_token[row0 + r + lr];
    if (tk < 0) tk = 0;
    aG[i] = Xb + (size_t)tk * DIM + lcx * 8;
    bG[i] = W1T + ((size_t)e * HDIM + n0 + r + lr) * DIM + lcx * 8;
    aL[i] = &As[r][0];
    bL[i] = &Bs[r][0];
  }

  int frow = lane & 15;
  int hi   = lane >> 4;
  int kxs  = (hi * 8) ^ ((lane & 7) << 3);

  f32x4 acc[4][4];
#pragma unroll
  for (int m = 0; m < 4; m++)
#pragma unroll
    for (int n = 0; n < 4; n++) acc[m][n] = 0.f;

  for (int k0 = 0; k0 < DIM; k0 += BK) {
#pragma unroll
    for (int i = 0; i < 4; i++) gload_lds16(aG[i] + k0, aL[i]);
#pragma unroll
    for (int i = 0; i < 4; i++) gload_lds16(bG[i] + k0, bL[i]);
    __syncthreads();
#pragma unroll
    for (int kk = 0; kk < 2; kk++) {
      int col = (kk * 32) ^ kxs;
      u32x4 a[4], b[4];
#pragma unroll
      for (int m = 0; m < 4; m++)
        a[m] = *(const u32x4*)&As[wr * 64 + m * 16 + frow][col];
#pragma unroll
      for (int n = 0; n < 4; n++)
        b[n] = *(const u32x4*)&Bs[wc * 64 + n * 16 + frow][col];
#pragma unroll
      for (int m = 0; m < 4; m++)
#pragma unroll
        for (int n = 0; n < 4; n++)
          acc[m][n] = mfma_bf16_16x16x32(a[m], b[n], acc[m][n]);
    }
    __syncthreads();
  }

  // LDS-staged epilogue: gelu -> bf16 -> [32][136] LDS chunk -> 256B rows
  float bias[4];
#pragma unroll
  for (int n = 0; n < 4; n++) bias[n] = b1[e * HDIM + n0 + wc * 64 + n * 16 + frow];
  unsigned short (*E)[136] = (unsigned short (*)[136])SMEM;
#pragma unroll
  for (int c0 = 0; c0 < 128; c0 += 32) {
    if (wr == (c0 >> 6)) {
      int mbase = (c0 & 63) >> 4;
#pragma unroll
      for (int mm = 0; mm < 2; mm++) {
        int m = mbase + mm;
#pragma unroll
        for (int n = 0; n < 4; n++)
#pragma unroll
          for (int j = 0; j < 4; j++)
            E[mm * 16 + hi * 4 + j][wc * 64 + n * 16 + frow] =
                f2bf(gelu_fast(acc[m][n][j] + bias[n]));
      }
    }
    __syncthreads();
#pragma unroll
    for (int p = 0; p < 2; p++) {
      int r  = p * 16 + (tid >> 4);
      int cc = (tid & 15) * 8;
      u32x4 v = *(const u32x4*)&E[r][cc];
      *(u32x4*)(Hbuf + (size_t)(row0 + c0 + r) * HDIM + n0 + cc) = v;
    }
    __syncthreads();
  }
}

// ---- GEMM2 split-K=2 (two-pass, no atomics): Ybuf[sp][slot] partials ------
__global__ __launch_bounds__(256) void gemm2_kernel(const unsigned short* __restrict__ Hbuf,
                                                    const unsigned short* __restrict__ W2T,
                                                    const float* __restrict__ b2,
                                                    const int* __restrict__ counts,
                                                    unsigned short* __restrict__ Ybuf) {
  __shared__ __align__(16) unsigned short As[BM][BK];
  __shared__ __align__(16) unsigned short Bs[BN][BK];
  int offs[NE + 1];
  load_offs(counts, offs);
  const int GY2 = (DIM / BN) * 2;   // 16: {8 n-tiles} x {2 K-splits}
  int lin = blockIdx.y * gridDim.x + blockIdx.x;
  int cpx = (TILES * GY2) >> 3;
  int wk  = (lin & 7) * cpx + (lin >> 3);
  int bx = wk / GY2;
  int rem = wk % GY2;
  int by = rem & 7, sp = rem >> 3;   // sp slowest: 8 consecutive share A K-half
  int kbase = sp * (HDIM / 2);

  int row0 = bx * BM;
  if (row0 >= offs[NE]) return;
  int e = 0;
#pragma unroll
  for (int i = 1; i < NE; i++) if (row0 >= offs[i]) e = i;
  int n0  = by * BN;
  int tid  = threadIdx.x;
  int lane = tid & 63;
  int w    = tid >> 6;
  int wr = tid >> 7;
  int wc = (tid >> 6) & 1;

  int lr  = lane >> 3;
  int lcx = (lane & 7) ^ lr;
  const unsigned short* aG[4];
  const unsigned short* bG[4];
  unsigned short* aL[4];
  unsigned short* bL[4];
#pragma unroll
  for (int i = 0; i < 4; i++) {
    int r = w * 32 + i * 8;
    aG[i] = Hbuf + (size_t)(row0 + r + lr) * HDIM + kbase + lcx * 8;
    bG[i] = W2T + ((size_t)e * DIM + n0 + r + lr) * HDIM + kbase + lcx * 8;
    aL[i] = &As[r][0];
    bL[i] = &Bs[r][0];
  }

  int frow = lane & 15;
  int hi   = lane >> 4;
  int kxs  = (hi * 8) ^ ((lane & 7) << 3);

  f32x4 acc[4][4];
#pragma unroll
  for (int m = 0; m < 4; m++)
#pragma unroll
    for (int n = 0; n < 4; n++) acc[m][n] = 0.f;

  for (int k0 = 0; k0 < HDIM / 2; k0 += BK) {
#pragma unroll
    for (int i = 0; i < 4; i++) gload_lds16(aG[i] + k0, aL[i]);
#pragma unroll
    for (int i = 0; i < 4; i++) gload_lds16(bG[i] + k0, bL[i]);
    __syncthreads();
#pragma unroll
    for (int kk = 0; kk < 2; kk++) {
      int col = (kk * 32) ^ kxs;
      u32x4 a[4], b[4];
#pragma unroll
      for (int m = 0; m < 4; m++)
        a[m] = *(const u32x4*)&As[wr * 64 + m * 16 + frow][col];
#pragma unroll
      for (int n = 0; n < 4; n++)
        b[n] = *(const u32x4*)&Bs[wc * 64 + n * 16 + frow][col];
#pragma unroll
      for (int m = 0; m < 4; m++)
#pragma unroll
        for (int n = 0; n < 4; n++)
          acc[m][n] = mfma_bf16_16x16x32(a[m], b[n], acc[m][n]);
    }
    __syncthreads();
  }

  // LDS-staged bf16 epilogue; bias added on split 1 only
  float bias[4];
#pragma unroll
  for (int n = 0; n < 4; n++)
    bias[n] = sp ? b2[e * DIM + n0 + wc * 64 + n * 16 + frow] : 0.f;
  unsigned short* Yp = Ybuf + (size_t)sp * SLOT_CAP * DIM;
  unsigned short (*E)[136] = (unsigned short (*)[136])(&As[0][0]);
#pragma unroll
  for (int c0 = 0; c0 < 128; c0 += 32) {
    if (wr == (c0 >> 6)) {
      int mbase = (c0 & 63) >> 4;
#pragma unroll
      for (int mm = 0; mm < 2; mm++) {
        int m = mbase + mm;
#pragma unroll
        for (int n = 0; n < 4; n++)
#pragma unroll
          for (int j = 0; j < 4; j++)
            E[mm * 16 + hi * 4 + j][wc * 64 + n * 16 + frow] =
                f2bf(acc[m][n][j] + bias[n]);
      }
    }
    __syncthreads();
#pragma unroll
    for (int p = 0; p < 2; p++) {
      int r  = p * 16 + (tid >> 4);
      int cc = (tid & 15) * 8;
      u32x4 v = *(const u32x4*)&E[r][cc];
      *(u32x4*)(Yp + (size_t)(row0 + c0 + r) * DIM + n0 + cc) = v;
    }
    __syncthreads();
  }
}

// ---- combine: out[t] = w0*(Y0[s0]+Y1[s0]) + w1*(Y0[s1]+Y1[s1]) ------------
__global__ __launch_bounds__(256) void combine_kernel(const unsigned short* __restrict__ Ybuf,
                                                      const int* __restrict__ tok_slot,
                                                      const float* __restrict__ tok_w,
                                                      float* __restrict__ out) {
  int t = blockIdx.x * 2 + (threadIdx.x >> 7);
  int c = (threadIdx.x & 127) * 8;
  int s0 = tok_slot[t * 2], s1 = tok_slot[t * 2 + 1];
  float w0 = tok_w[t * 2], w1 = tok_w[t * 2 + 1];
  const unsigned short* Y1 = Ybuf + (size_t)SLOT_CAP * DIM;
  u32x4 p0 = *(const u32x4*)(Ybuf + (size_t)s0 * DIM + c);
  u32x4 p1 = *(const u32x4*)(Y1   + (size_t)s0 * DIM + c);
  u32x4 q0 = *(const u32x4*)(Ybuf + (size_t)s1 * DIM + c);
  u32x4 q1 = *(const u32x4*)(Y1   + (size_t)s1 * DIM + c);
  float r[8];
#pragma unroll
  for (int k = 0; k < 4; k++) {
    union { unsigned int u; float f; } a;
#pragma unroll
    for (int hl = 0; hl < 2; hl++) {
      a.u = hl ? (p0[k] & 0xFFFF0000u) : (p0[k] << 16); float vp0 = a.f;
      a.u = hl ? (p1[k] & 0xFFFF0000u) : (p1[k] << 16); float vp1 = a.f;
      a.u = hl ? (q0[k] & 0xFFFF0000u) : (q0[k] << 16); float vq0 = a.f;
      a.u = hl ? (q1[k] & 0xFFFF0000u) : (q1[k] << 16); float vq1 = a.f;
      r[2 * k + hl] = w0 * (vp0 + vp1) + w1 * (vq0 + vq1);
    }
  }
  float* o = out + (size_t)t * DIM + c;
  *(f32x4*)o       = *(f32x4*)&r[0];
  *(f32x4*)(o + 4) = *(f32x4*)&r[4];
}

extern "C" void kernel_launch(void* const* d_in, const int* in_sizes, int n_in,
                              void* d_out, int out_size, void* d_ws, size_t ws_size,
                              hipStream_t stream) {
  (void)in_sizes; (void)n_in; (void)out_size;
  const float* x  = (const float*)d_in[0];
  const float* Wg = (const float*)d_in[1];
  const float* W1 = (const float*)d_in[2];
  const float* b1 = (const float*)d_in[3];
  const float* W2 = (const float*)d_in[4];
  const float* b2 = (const float*)d_in[5];
  float* out = (float*)d_out;

  char* ws = (char*)d_ws;
  size_t off = 0;
  auto take = [&](size_t bytes) -> char* {
    char* p = ws + off;
    off += (bytes + 255) & ~(size_t)255;
    return p;
  };
  unsigned short* W1T  = (unsigned short*)take((size_t)NE * DIM * HDIM * 2);
  unsigned short* W2T  = (unsigned short*)take((size_t)NE * DIM * HDIM * 2);
  unsigned short* Xb   = (unsigned short*)take((size_t)T_TOK * DIM * 2);
  unsigned short* Hbuf = (unsigned short*)take((size_t)SLOT_CAP * HDIM * 2);
  unsigned short* Ybuf = (unsigned short*)take((size_t)2 * SLOT_CAP * DIM * 2);
  int*   slot_token = (int*)take(SLOT_CAP * 4);
  int*   tok_e      = (int*)take(T_TOK * 2 * 4);
  float* tok_w      = (float*)take(T_TOK * 2 * 4);
  int*   tok_slot   = (int*)take(T_TOK * 2 * 4);
  int*   cnt_cur    = (int*)take(256);
  int*   counts  = cnt_cur;        // 8 ints
  int*   cursors = cnt_cur + 32;   // 8 ints (128B-separated)

  if (off > ws_size) {
    hipMemsetAsync(d_out, 0, (size_t)out_size * 4, stream);
    return;
  }

  hipMemsetAsync(cnt_cur, 0, 256, stream);
  prep_kernel<<<T_TOK / 4 + 8192, 256, 0, stream>>>(x, Wg, tok_e, tok_w, Xb,
                                                    counts, W1, W1T);
  scatter_kernel<<<T_TOK / 256, 256, 0, stream>>>(tok_e, counts, cursors,
                                                  slot_token, tok_slot);
  gemm1_kernel<<<G1BLKS + W2BLKS, 256, 0, stream>>>(Xb, W1T, b1, slot_token,
                                                    counts, Hbuf, W2, W2T);
  gemm2_kernel<<<dim3(TILES, 16), 256, 0, stream>>>(Hbuf, W2T, b2, counts, Ybuf);
  combine_kernel<<<T_TOK / 2, 256, 0, stream>>>(Ybuf, tok_slot, tok_w, out);
}

// Round 10
// 476.107 us; speedup vs baseline: 1.6806x; 1.0125x over previous
//
#include <hip/hip_runtime.h>

#define T_TOK 8192
#define DIM   1024
#define HDIM  4096
#define NE    8
#define BK    64
#define BM    128
#define BN    128
#define SLOT_CAP (T_TOK * 2 + NE * BM)   // 17408 = 136*128
#define TILES (SLOT_CAP / BM)            // 136
#define G1BLKS (TILES * (HDIM / BN))     // 4352 gemm1 tile-blocks
#define W2BLKS ((HDIM / 64) * (DIM / 64) * NE)  // 8192 transpose blocks

typedef float        f32x4 __attribute__((ext_vector_type(4)));
typedef unsigned int u32x2 __attribute__((ext_vector_type(2)));
typedef unsigned int u32x4 __attribute__((ext_vector_type(4)));

// hardware bf16 convert (RNE, identical rounding to the integer version)
__device__ inline unsigned short f2bf(float f) {
  unsigned int r;
  asm("v_cvt_pk_bf16_f32 %0, %1, %1" : "=v"(r) : "v"(f));
  return (unsigned short)r;
}
__device__ inline unsigned int f2bf2(float lo, float hi) {
  unsigned int r;
  asm("v_cvt_pk_bf16_f32 %0, %1, %2" : "=v"(r) : "v"(lo), "v"(hi));
  return r;
}

__device__ inline f32x4 mfma_bf16_16x16x32(u32x4 a, u32x4 b, f32x4 c) {
  asm("v_mfma_f32_16x16x32_bf16 %0, %1, %2, %0" : "+v"(c) : "v"(a), "v"(b));
  return c;
}

__device__ inline void gload_lds16(const void* g, void* l) {
  __builtin_amdgcn_global_load_lds(
      (const __attribute__((address_space(1))) void*)g,
      (__attribute__((address_space(3))) void*)l, 16, 0, 0);
}

// gelu(v) = v * sigmoid(2*c*(v + 0.044715 v^3))  (tanh-form identity)
__device__ inline float gelu_fast(float v) {
  const float c2 = 1.5957691216057308f;   // 2*sqrt(2/pi)
  float z = c2 * (v + 0.044715f * v * v * v);
  return v / (1.0f + __expf(-z));
}

// padded (128-aligned) expert segment prefix, recomputed locally
__device__ inline void load_offs(const int* __restrict__ counts, int* offs) {
  offs[0] = 0;
#pragma unroll
  for (int e = 0; e < NE; e++)
    offs[e + 1] = offs[e] + ((counts[e] + BM - 1) / BM) * BM;
}

// ---- 64x64 transpose tile body: src fp32 [E][R][C] -> dst bf16 [E][C][R] --
__device__ void transpose_body(const float* __restrict__ src,
                               unsigned short* __restrict__ dst,
                               int R, int C, int e, int c0, int r0,
                               float (*tile)[65]) {
  int c  = threadIdx.x & 63, r4 = threadIdx.x >> 6;
  const float* s = src + (size_t)e * R * C;
#pragma unroll
  for (int i = 0; i < 16; i++) {
    int r = r4 + i * 4;
    tile[r][c] = s[(size_t)(r0 + r) * C + (c0 + c)];
  }
  __syncthreads();
  unsigned short* d = dst + (size_t)e * R * C;
  int rbase = (threadIdx.x & 7) * 8;
#pragma unroll
  for (int g = 0; g < 2; g++) {
    int cc = (threadIdx.x >> 3) + g * 32;
    u32x4 v;
#pragma unroll
    for (int k = 0; k < 4; k++)
      v[k] = f2bf2(tile[rbase + 2 * k][cc], tile[rbase + 2 * k + 1][cc]);
    *(u32x4*)(d + (size_t)(c0 + cc) * R + (r0 + rbase)) = v;
  }
}

// ===========================================================================
// prep: routing (blocks 0..2047) + transpose W1 (2048..10239).
// W2's transpose lives in gemm1's grid tail (r9 backfill, verified).
// ===========================================================================
__global__ __launch_bounds__(256) void prep_kernel(const float* __restrict__ x,
                                                   const float* __restrict__ Wg,
                                                   int* __restrict__ tok_e,
                                                   float* __restrict__ tok_w,
                                                   unsigned short* __restrict__ xb,
                                                   int* __restrict__ counts,
                                                   const float* __restrict__ W1,
                                                   unsigned short* __restrict__ W1T) {
  __shared__ float tile[64][65];
  __shared__ int h[NE];
  int bid = blockIdx.x;
  if (bid < T_TOK / 4) {
    // ---- routing + fused x->bf16 convert + histogram ----
    if (threadIdx.x < NE) h[threadIdx.x] = 0;
    __syncthreads();
    int tok  = bid * 4 + (threadIdx.x >> 6);
    int lane = threadIdx.x & 63;
    const float* xr = x + (size_t)tok * DIM;
    float acc[NE];
#pragma unroll
    for (int e = 0; e < NE; e++) acc[e] = 0.f;
    for (int d = lane; d < DIM; d += 64) {
      float xv = xr[d];
      const float* wr = Wg + d * NE;
#pragma unroll
      for (int e = 0; e < NE; e++) acc[e] += xv * wr[e];
    }
#pragma unroll
    for (int e = 0; e < NE; e++) {
#pragma unroll
      for (int off = 32; off > 0; off >>= 1) acc[e] += __shfl_xor(acc[e], off);
    }
    if (lane == 0) {
      int i0 = 0;
#pragma unroll
      for (int e = 1; e < NE; e++) if (acc[e] > acc[i0]) i0 = e;
      int i1 = (i0 == 0) ? 1 : 0;
#pragma unroll
      for (int e = 0; e < NE; e++) if (e != i0 && acc[e] > acc[i1]) i1 = e;
      float w0 = 1.0f / (1.0f + expf(acc[i1] - acc[i0]));
      tok_e[tok * 2]     = i0;
      tok_e[tok * 2 + 1] = i1;
      tok_w[tok * 2]     = w0;
      tok_w[tok * 2 + 1] = 1.0f - w0;
      atomicAdd(&h[i0], 1);
      atomicAdd(&h[i1], 1);
    }
    unsigned short* xo = xb + (size_t)tok * DIM;
#pragma unroll
    for (int i = 0; i < 4; i++) {
      f32x4 v = *(const f32x4*)(xr + lane * 16 + i * 4);
      u32x2 p;
      p[0] = f2bf2(v[0], v[1]);
      p[1] = f2bf2(v[2], v[3]);
      *(u32x2*)(xo + lane * 16 + i * 4) = p;
    }
    __syncthreads();
    if (threadIdx.x < NE) atomicAdd(&counts[threadIdx.x], h[threadIdx.x]);
  } else {
    // ---- W1 [E][1024][4096] -> W1T [E][4096][1024] bf16 ----
    int idx = bid - T_TOK / 4;
    transpose_body(W1, W1T, DIM, HDIM, idx >> 10, (idx & 63) * 64,
                   ((idx >> 6) & 15) * 64, tile);
  }
}

// ---- scatter (wave-ballot aggregated) + padding init (block 0) ------------
__global__ __launch_bounds__(256) void scatter_kernel(const int* __restrict__ tok_e,
                                                      const int* __restrict__ counts,
                                                      int* __restrict__ cursors,
                                                      int* __restrict__ slot_token,
                                                      int* __restrict__ tok_slot) {
  int offs[NE + 1];
  load_offs(counts, offs);
  if (blockIdx.x == 0) {
#pragma unroll
    for (int e = 0; e < NE; e++)
      for (int s = offs[e] + counts[e] + threadIdx.x; s < offs[e + 1]; s += 256)
        slot_token[s] = -1;
  }
  int t = blockIdx.x * 256 + threadIdx.x;
  int lane = threadIdx.x & 63;
#pragma unroll
  for (int j = 0; j < 2; j++) {
    int e = tok_e[t * 2 + j];
#pragma unroll
    for (int ee = 0; ee < NE; ee++) {
      unsigned long long m = __ballot(e == ee);
      if (e == ee) {
        int leader = __ffsll(m) - 1;
        int base = 0;
        if (lane == leader) base = atomicAdd(&cursors[ee], (int)__popcll(m));
        base = __shfl(base, leader);
        int pos = base + (int)__popcll(m & ((1ULL << lane) - 1ULL));
        int s = offs[ee] + pos;
        slot_token[s] = t;
        tok_slot[t * 2 + j] = s;
      }
    }
  }
}

// ===========================================================================
// GEMM core (m97): 128x128 tile, BK=64, 4 waves, global_load_lds width 16
// into LINEAR [128][64] bf16 LDS; XOR swizzle baked into the GLOBAL source
// chunk; ds_read un-swizzles (rule #21).  0 main-loop bank conflicts (r2).
// A-PANEL-MAJOR XCD swizzle (r6 verified).  W2-transpose backfill (r9).
// ===========================================================================

// ---- GEMM1 + W2-transpose backfill ----------------------------------------
__global__ __launch_bounds__(256) void gemm1_kernel(const unsigned short* __restrict__ Xb,
                                                    const unsigned short* __restrict__ W1T,
                                                    const float* __restrict__ b1,
                                                    const int* __restrict__ slot_token,
                                                    const int* __restrict__ counts,
                                                    unsigned short* __restrict__ Hbuf,
                                                    const float* __restrict__ W2,
                                                    unsigned short* __restrict__ W2T) {
  __shared__ __align__(16) unsigned short SMEM[2 * BM * BK];   // 32 KB overlay
  if (blockIdx.x >= G1BLKS) {
    // ---- W2 [E][4096][1024] -> W2T [E][1024][4096] bf16 ----
    int idx = blockIdx.x - G1BLKS;
    transpose_body(W2, W2T, HDIM, DIM, idx >> 10, (idx & 15) * 64,
                   ((idx >> 4) & 63) * 64, (float (*)[65])SMEM);
    return;
  }
  unsigned short (*As)[BK] = (unsigned short (*)[BK])SMEM;
  unsigned short (*Bs)[BK] = (unsigned short (*)[BK])(SMEM + BM * BK);
  int offs[NE + 1];
  load_offs(counts, offs);
  const int GY = HDIM / BN;   // 32
  int lin = blockIdx.x;
  int cpx = G1BLKS >> 3;
  int wk  = (lin & 7) * cpx + (lin >> 3);
  int bx = wk / GY, by = wk % GY;

  int row0 = bx * BM;
  if (row0 >= offs[NE]) return;
  int e = 0;
#pragma unroll
  for (int i = 1; i < NE; i++) if (row0 >= offs[i]) e = i;
  int n0  = by * BN;
  int tid  = threadIdx.x;
  int lane = tid & 63;
  int w    = tid >> 6;
  int wr = tid >> 7;
  int wc = (tid >> 6) & 1;

  int lr  = lane >> 3;
  int lcx = (lane & 7) ^ lr;
  const unsigned short* aG[4];
  const unsigned short* bG[4];
  unsigned short* aL[4];
  unsigned short* bL[4];
#pragma unroll
  for (int i = 0; i < 4; i++) {
    int r = w * 32 + i * 8;
    int tk = slot_token[row0 + r + lr];
    if (tk < 0) tk = 0;
    aG[i] = Xb + (size_t)tk * DIM + lcx * 8;
    bG[i] = W1T + ((size_t)e * HDIM + n0 + r + lr) * DIM + lcx * 8;
    aL[i] = &As[r][0];
    bL[i] = &Bs[r][0];
  }

  int frow = lane & 15;
  int hi   = lane >> 4;
  int kxs  = (hi * 8) ^ ((lane & 7) << 3);

  f32x4 acc[4][4];
#pragma unroll
  for (int m = 0; m < 4; m++)
#pragma unroll
    for (int n = 0; n < 4; n++) acc[m][n] = 0.f;

  for (int k0 = 0; k0 < DIM; k0 += BK) {
#pragma unroll
    for (int i = 0; i < 4; i++) gload_lds16(aG[i] + k0, aL[i]);
#pragma unroll
    for (int i = 0; i < 4; i++) gload_lds16(bG[i] + k0, bL[i]);
    __syncthreads();
#pragma unroll
    for (int kk = 0; kk < 2; kk++) {
      int col = (kk * 32) ^ kxs;
      u32x4 a[4], b[4];
#pragma unroll
      for (int m = 0; m < 4; m++)
        a[m] = *(const u32x4*)&As[wr * 64 + m * 16 + frow][col];
#pragma unroll
      for (int n = 0; n < 4; n++)
        b[n] = *(const u32x4*)&Bs[wc * 64 + n * 16 + frow][col];
#pragma unroll
      for (int m = 0; m < 4; m++)
#pragma unroll
        for (int n = 0; n < 4; n++)
          acc[m][n] = mfma_bf16_16x16x32(a[m], b[n], acc[m][n]);
    }
    __syncthreads();
  }

  // LDS-staged epilogue: gelu -> bf16 -> [64][136] LDS chunk -> 256B rows
  // (2 chunks of 64 rows: 17.4 KB in the 32 KB overlay, half the barriers)
  float bias[4];
#pragma unroll
  for (int n = 0; n < 4; n++) bias[n] = b1[e * HDIM + n0 + wc * 64 + n * 16 + frow];
  unsigned short (*E)[136] = (unsigned short (*)[136])SMEM;
#pragma unroll
  for (int c0 = 0; c0 < 128; c0 += 64) {
    if (wr == (c0 >> 6)) {
#pragma unroll
      for (int m = 0; m < 4; m++)
#pragma unroll
        for (int n = 0; n < 4; n++)
#pragma unroll
          for (int j = 0; j < 4; j++)
            E[m * 16 + hi * 4 + j][wc * 64 + n * 16 + frow] =
                f2bf(gelu_fast(acc[m][n][j] + bias[n]));
    }
    __syncthreads();
#pragma unroll
    for (int p = 0; p < 4; p++) {
      int r  = p * 16 + (tid >> 4);
      int cc = (tid & 15) * 8;
      u32x4 v = *(const u32x4*)&E[r][cc];
      *(u32x4*)(Hbuf + (size_t)(row0 + c0 + r) * HDIM + n0 + cc) = v;
    }
    __syncthreads();
  }
}

// ---- GEMM2 split-K=2 (two-pass, no atomics): Ybuf[sp][slot] partials ------
__global__ __launch_bounds__(256) void gemm2_kernel(const unsigned short* __restrict__ Hbuf,
                                                    const unsigned short* __restrict__ W2T,
                                                    const float* __restrict__ b2,
                                                    const int* __restrict__ counts,
                                                    unsigned short* __restrict__ Ybuf) {
  __shared__ __align__(16) unsigned short As[BM][BK];
  __shared__ __align__(16) unsigned short Bs[BN][BK];
  int offs[NE + 1];
  load_offs(counts, offs);
  const int GY2 = (DIM / BN) * 2;   // 16: {8 n-tiles} x {2 K-splits}
  int lin = blockIdx.y * gridDim.x + blockIdx.x;
  int cpx = (TILES * GY2) >> 3;
  int wk  = (lin & 7) * cpx + (lin >> 3);
  int bx = wk / GY2;
  int rem = wk % GY2;
  int by = rem & 7, sp = rem >> 3;   // sp slowest: 8 consecutive share A K-half
  int kbase = sp * (HDIM / 2);

  int row0 = bx * BM;
  if (row0 >= offs[NE]) return;
  int e = 0;
#pragma unroll
  for (int i = 1; i < NE; i++) if (row0 >= offs[i]) e = i;
  int n0  = by * BN;
  int tid  = threadIdx.x;
  int lane = tid & 63;
  int w    = tid >> 6;
  int wr = tid >> 7;
  int wc = (tid >> 6) & 1;

  int lr  = lane >> 3;
  int lcx = (lane & 7) ^ lr;
  const unsigned short* aG[4];
  const unsigned short* bG[4];
  unsigned short* aL[4];
  unsigned short* bL[4];
#pragma unroll
  for (int i = 0; i < 4; i++) {
    int r = w * 32 + i * 8;
    aG[i] = Hbuf + (size_t)(row0 + r + lr) * HDIM + kbase + lcx * 8;
    bG[i] = W2T + ((size_t)e * DIM + n0 + r + lr) * HDIM + kbase + lcx * 8;
    aL[i] = &As[r][0];
    bL[i] = &Bs[r][0];
  }

  int frow = lane & 15;
  int hi   = lane >> 4;
  int kxs  = (hi * 8) ^ ((lane & 7) << 3);

  f32x4 acc[4][4];
#pragma unroll
  for (int m = 0; m < 4; m++)
#pragma unroll
    for (int n = 0; n < 4; n++) acc[m][n] = 0.f;

  for (int k0 = 0; k0 < HDIM / 2; k0 += BK) {
#pragma unroll
    for (int i = 0; i < 4; i++) gload_lds16(aG[i] + k0, aL[i]);
#pragma unroll
    for (int i = 0; i < 4; i++) gload_lds16(bG[i] + k0, bL[i]);
    __syncthreads();
#pragma unroll
    for (int kk = 0; kk < 2; kk++) {
      int col = (kk * 32) ^ kxs;
      u32x4 a[4], b[4];
#pragma unroll
      for (int m = 0; m < 4; m++)
        a[m] = *(const u32x4*)&As[wr * 64 + m * 16 + frow][col];
#pragma unroll
      for (int n = 0; n < 4; n++)
        b[n] = *(const u32x4*)&Bs[wc * 64 + n * 16 + frow][col];
#pragma unroll
      for (int m = 0; m < 4; m++)
#pragma unroll
        for (int n = 0; n < 4; n++)
          acc[m][n] = mfma_bf16_16x16x32(a[m], b[n], acc[m][n]);
    }
    __syncthreads();
  }

  // LDS-staged bf16 epilogue; bias added on split 1 only
  float bias[4];
#pragma unroll
  for (int n = 0; n < 4; n++)
    bias[n] = sp ? b2[e * DIM + n0 + wc * 64 + n * 16 + frow] : 0.f;
  unsigned short* Yp = Ybuf + (size_t)sp * SLOT_CAP * DIM;
  unsigned short (*E)[136] = (unsigned short (*)[136])(&As[0][0]);
#pragma unroll
  for (int c0 = 0; c0 < 128; c0 += 64) {
    if (wr == (c0 >> 6)) {
#pragma unroll
      for (int m = 0; m < 4; m++)
#pragma unroll
        for (int n = 0; n < 4; n++)
#pragma unroll
          for (int j = 0; j < 4; j++)
            E[m * 16 + hi * 4 + j][wc * 64 + n * 16 + frow] =
                f2bf(acc[m][n][j] + bias[n]);
    }
    __syncthreads();
#pragma unroll
    for (int p = 0; p < 4; p++) {
      int r  = p * 16 + (tid >> 4);
      int cc = (tid & 15) * 8;
      u32x4 v = *(const u32x4*)&E[r][cc];
      *(u32x4*)(Yp + (size_t)(row0 + c0 + r) * DIM + n0 + cc) = v;
    }
    __syncthreads();
  }
}

// ---- combine: out[t] = w0*(Y0[s0]+Y1[s0]) + w1*(Y0[s1]+Y1[s1]) ------------
__global__ __launch_bounds__(256) void combine_kernel(const unsigned short* __restrict__ Ybuf,
                                                      const int* __restrict__ tok_slot,
                                                      const float* __restrict__ tok_w,
                                                      float* __restrict__ out) {
  int t = blockIdx.x * 2 + (threadIdx.x >> 7);
  int c = (threadIdx.x & 127) * 8;
  int s0 = tok_slot[t * 2], s1 = tok_slot[t * 2 + 1];
  float w0 = tok_w[t * 2], w1 = tok_w[t * 2 + 1];
  const unsigned short* Y1 = Ybuf + (size_t)SLOT_CAP * DIM;
  u32x4 p0 = *(const u32x4*)(Ybuf + (size_t)s0 * DIM + c);
  u32x4 p1 = *(const u32x4*)(Y1   + (size_t)s0 * DIM + c);
  u32x4 q0 = *(const u32x4*)(Ybuf + (size_t)s1 * DIM + c);
  u32x4 q1 = *(const u32x4*)(Y1   + (size_t)s1 * DIM + c);
  float r[8];
#pragma unroll
  for (int k = 0; k < 4; k++) {
    union { unsigned int u; float f; } a;
#pragma unroll
    for (int hl = 0; hl < 2; hl++) {
      a.u = hl ? (p0[k] & 0xFFFF0000u) : (p0[k] << 16); float vp0 = a.f;
      a.u = hl ? (p1[k] & 0xFFFF0000u) : (p1[k] << 16); float vp1 = a.f;
      a.u = hl ? (q0[k] & 0xFFFF0000u) : (q0[k] << 16); float vq0 = a.f;
      a.u = hl ? (q1[k] & 0xFFFF0000u) : (q1[k] << 16); float vq1 = a.f;
      r[2 * k + hl] = w0 * (vp0 + vp1) + w1 * (vq0 + vq1);
    }
  }
  float* o = out + (size_t)t * DIM + c;
  *(f32x4*)o       = *(f32x4*)&r[0];
  *(f32x4*)(o + 4) = *(f32x4*)&r[4];
}

extern "C" void kernel_launch(void* const* d_in, const int* in_sizes, int n_in,
                              void* d_out, int out_size, void* d_ws, size_t ws_size,
                              hipStream_t stream) {
  (void)in_sizes; (void)n_in; (void)out_size;
  const float* x  = (const float*)d_in[0];
  const float* Wg = (const float*)d_in[1];
  const float* W1 = (const float*)d_in[2];
  const float* b1 = (const float*)d_in[3];
  const float* W2 = (const float*)d_in[4];
  const float* b2 = (const float*)d_in[5];
  float* out = (float*)d_out;

  char* ws = (char*)d_ws;
  size_t off = 0;
  auto take = [&](size_t bytes) -> char* {
    char* p = ws + off;
    off += (bytes + 255) & ~(size_t)255;
    return p;
  };
  unsigned short* W1T  = (unsigned short*)take((size_t)NE * DIM * HDIM * 2);
  unsigned short* W2T  = (unsigned short*)take((size_t)NE * DIM * HDIM * 2);
  unsigned short* Xb   = (unsigned short*)take((size_t)T_TOK * DIM * 2);
  unsigned short* Hbuf = (unsigned short*)take((size_t)SLOT_CAP * HDIM * 2);
  unsigned short* Ybuf = (unsigned short*)take((size_t)2 * SLOT_CAP * DIM * 2);
  int*   slot_token = (int*)take(SLOT_CAP * 4);
  int*   tok_e      = (int*)take(T_TOK * 2 * 4);
  float* tok_w      = (float*)take(T_TOK * 2 * 4);
  int*   tok_slot   = (int*)take(T_TOK * 2 * 4);
  int*   cnt_cur    = (int*)take(256);
  int*   counts  = cnt_cur;        // 8 ints
  int*   cursors = cnt_cur + 32;   // 8 ints (128B-separated)

  if (off > ws_size) {
    hipMemsetAsync(d_out, 0, (size_t)out_size * 4, stream);
    return;
  }

  hipMemsetAsync(cnt_cur, 0, 256, stream);
  prep_kernel<<<T_TOK / 4 + 8192, 256, 0, stream>>>(x, Wg, tok_e, tok_w, Xb,
                                                    counts, W1, W1T);
  scatter_kernel<<<T_TOK / 256, 256, 0, stream>>>(tok_e, counts, cursors,
                                                  slot_token, tok_slot);
  gemm1_kernel<<<G1BLKS + W2BLKS, 256, 0, stream>>>(Xb, W1T, b1, slot_token,
                                                    counts, Hbuf, W2, W2T);
  gemm2_kernel<<<dim3(TILES, 16), 256, 0, stream>>>(Hbuf, W2T, b2, counts, Ybuf);
  combine_kernel<<<T_TOK / 2, 256, 0, stream>>>(Ybuf, tok_slot, tok_w, out);
}